// Round 5
// baseline (11853.223 us; speedup 1.0000x reference)
//
#include <hip/hip_runtime.h>
#include <math.h>

typedef long long ll;

#define BN 65536LL
#define LOSS_OFF (BN * 1024LL)
#define IDX_OFF  (LOSS_OFF + 1LL)

// ---- workspace layout (float offsets) ----
#define WF_W1 0LL                          // B x 512 scratch (ws slot S2)
#define WF_RT (WF_W1 + BN * 512LL)         // rec_table 2048 x 1024
#define WF_CN (WF_RT + 2048LL * 1024LL)    // cnorm 2048 (fp32)
#define WF_LP (WF_CN + 2048LL)             // loss partials 2048 doubles
// total ~143 MB (same as round 4)

// =================== k_mm2: Y = fl(fl(A@W^T)+b)[+resid], optional fused LN ===================
// 256 threads, 32 rows x 512 cols per block; thread (tx,ty): rows ty*4+i, cols tx+32*c.
// fp64 accumulation in fixed kc->j order (bit-identical to round 4 per element),
// fp32 rounding at every np op boundary.
// mode 0: raw -> Y.  mode 1: raw -> Y, LN(raw) -> Y2.  mode 2: relu(LN(raw)) -> Y.
__global__ __launch_bounds__(256)
void k_mm2(const float* __restrict__ A0, const float* __restrict__ A1, int K,
           const float* __restrict__ W, const float* __restrict__ bias,
           const float* __restrict__ resid,
           const float* __restrict__ lnw, const float* __restrict__ lnb,
           int mode, float* __restrict__ Y, float* __restrict__ Y2)
{
  __shared__ float As[32][17];
  __shared__ float Bs[16][516];
  __shared__ double red[32][33];
  __shared__ float msh[32], rsh[32];
  __shared__ float lw[512], lb[512];
  const int tid = threadIdx.x;
  const int tx = tid & 31, ty = tid >> 5;   // ty 0..7
  const ll r0 = (ll)blockIdx.x * 32;

  if (mode != 0) {
    lw[tid] = lnw[tid]; lw[tid + 256] = lnw[tid + 256];
    lb[tid] = lnb[tid]; lb[tid + 256] = lnb[tid + 256];
  }

  double acc[4][16];
#pragma unroll
  for (int i = 0; i < 4; ++i)
#pragma unroll
    for (int c = 0; c < 16; ++c) acc[i][c] = 0.0;

  for (int kc = 0; kc < K; kc += 16) {
    // stage A (32 rows x 16 k) — 128 threads, float4
    if (tid < 128) {
      const int rr = tid >> 2, q = tid & 3;
      const int col = kc + q * 4;
      const float* src;
      if (A1 == nullptr) src = A0 + (r0 + rr) * (ll)K + col;
      else if (col < 512) src = A0 + (r0 + rr) * 512LL + col;
      else src = A1 + (r0 + rr) * 512LL + (col - 512);
      const float4 v = *(const float4*)src;
      As[rr][q*4+0] = v.x; As[rr][q*4+1] = v.y; As[rr][q*4+2] = v.z; As[rr][q*4+3] = v.w;
    }
    // stage B: Bs[jj][col] = W[col*K + kc + jj]
#pragma unroll
    for (int m = 0; m < 8; ++m) {
      const int l = m * 256 + tid;
      const int c = l >> 2, q = l & 3;
      const float4 v = *(const float4*)(W + (ll)c * K + kc + q * 4);
      Bs[q*4+0][c] = v.x; Bs[q*4+1][c] = v.y; Bs[q*4+2][c] = v.z; Bs[q*4+3][c] = v.w;
    }
    __syncthreads();
#pragma unroll
    for (int j = 0; j < 16; ++j) {
      const double a0 = (double)As[ty*4+0][j];
      const double a1 = (double)As[ty*4+1][j];
      const double a2 = (double)As[ty*4+2][j];
      const double a3 = (double)As[ty*4+3][j];
      const float* bp = &Bs[j][tx];
#pragma unroll
      for (int c = 0; c < 16; ++c) {
        const double bb = (double)bp[c*32];
        acc[0][c] = fma(a0, bb, acc[0][c]);
        acc[1][c] = fma(a1, bb, acc[1][c]);
        acc[2][c] = fma(a2, bb, acc[2][c]);
        acc[3][c] = fma(a3, bb, acc[3][c]);
      }
    }
    __syncthreads();
  }

  // epilogue: fl at each np op boundary
  float o[4][16];
#pragma unroll
  for (int i = 0; i < 4; ++i) {
    const int row = ty*4 + i;
#pragma unroll
    for (int c = 0; c < 16; ++c) {
      const int col = tx + 32*c;
      const float mm = (float)acc[i][c];      // fl(matmul)
      const float y1 = mm + bias[col];        // fl(+bias)
      o[i][c] = resid ? (resid[(r0 + row) * 512LL + col] + y1) : y1;  // fl(resid+.)
    }
  }

  if (mode != 2) {
#pragma unroll
    for (int i = 0; i < 4; ++i) {
      const int row = ty*4 + i;
#pragma unroll
      for (int c = 0; c < 16; ++c)
        Y[(r0 + row) * 512LL + tx + 32*c] = o[i][c];
    }
  }
  if (mode == 0) return;

  // fused LN (np-fp32 boundary chain, fp64 sums)
#pragma unroll
  for (int i = 0; i < 4; ++i) {
    double s = 0.0;
#pragma unroll
    for (int c = 0; c < 16; ++c) s += (double)o[i][c];
    red[ty*4+i][tx] = s;
  }
  __syncthreads();
  if (tid < 32) {
    double s = 0.0;
    for (int x = 0; x < 32; ++x) s += red[tid][x];
    msh[tid] = (float)(s * (1.0 / 512.0));
  }
  __syncthreads();
  float xm[4][16];
#pragma unroll
  for (int i = 0; i < 4; ++i) {
    const float m32 = msh[ty*4+i];
    double s2 = 0.0;
#pragma unroll
    for (int c = 0; c < 16; ++c) {
      xm[i][c] = o[i][c] - m32;               // fp32
      const float sq = xm[i][c] * xm[i][c];   // fp32
      s2 += (double)sq;
    }
    red[ty*4+i][tx] = s2;
  }
  __syncthreads();
  if (tid < 32) {
    double s = 0.0;
    for (int x = 0; x < 32; ++x) s += red[tid][x];
    const float v32 = (float)(s * (1.0 / 512.0));
    const float a32 = v32 + 1e-5f;
    const float sq32 = (float)sqrt((double)a32);
    rsh[tid] = (float)(1.0 / (double)sq32);
  }
  __syncthreads();
  {
    float* dst = (mode == 1) ? Y2 : Y;
#pragma unroll
    for (int i = 0; i < 4; ++i) {
      const int row = ty*4 + i;
      const float rs = rsh[row];
#pragma unroll
      for (int c = 0; c < 16; ++c) {
        const int col = tx + 32*c;
        float v = ((xm[i][c] * rs) * lw[col]) + lb[col];
        if (mode == 2) v = fmaxf(v, 0.f);
        dst[(r0 + row) * 512LL + col] = v;
      }
    }
  }
}

// =================== k_ln (verbatim round 4; used for lnt1) ===================
__global__ __launch_bounds__(256)
void k_ln(const float* __restrict__ X, const float* __restrict__ w,
          const float* __restrict__ b, float* __restrict__ Y, int relu)
{
  const int tid = threadIdx.x;
  const int lane = tid & 63, wid = tid >> 6;
  const ll row = (ll)blockIdx.x * 4 + wid;
  const ll base = row * 512;

  float xv[8];
#pragma unroll
  for (int j = 0; j < 8; ++j) xv[j] = X[base + j*64 + lane];

  double s = 0.0;
#pragma unroll
  for (int j = 0; j < 8; ++j) s += (double)xv[j];
#pragma unroll
  for (int off = 32; off > 0; off >>= 1) s += __shfl_down(s, off, 64);
  s = __shfl(s, 0, 64);
  const float m32 = (float)(s * (1.0 / 512.0));

  float xm[8];
  double s2 = 0.0;
#pragma unroll
  for (int j = 0; j < 8; ++j) {
    xm[j] = xv[j] - m32;
    const float sq = xm[j] * xm[j];
    s2 += (double)sq;
  }
#pragma unroll
  for (int off = 32; off > 0; off >>= 1) s2 += __shfl_down(s2, off, 64);
  s2 = __shfl(s2, 0, 64);
  const float v32 = (float)(s2 * (1.0 / 512.0));
  const float a32 = v32 + 1e-5f;
  const float sq32 = (float)sqrt((double)a32);
  const float rs32 = (float)(1.0 / (double)sq32);

#pragma unroll
  for (int j = 0; j < 8; ++j) {
    float o = ((xm[j] * rs32) * w[j*64 + lane]) + b[j*64 + lane];
    if (relu) o = fmaxf(o, 0.f);
    Y[base + j*64 + lane] = o;
  }
}

// =================== k_pre (verbatim round 4) ===================
__global__ __launch_bounds__(256)
void k_pre(const float* __restrict__ cbk, const float* __restrict__ d_w1,
           const float* __restrict__ d_b1, const float* __restrict__ d_w2,
           const float* __restrict__ d_b2,
           float* __restrict__ rect, float* __restrict__ cnorm)
{
  __shared__ float cbs16[16][68];
  __shared__ float pbuf[16][516];
  const int tid = threadIdx.x;
  const int bb = blockIdx.x;

  if (bb < 128) {
    const int e0 = bb * 16;
    {
      const int e = tid >> 4, q = tid & 15;
      const float4 v = *(const float4*)(cbk + (ll)(e0 + e) * 64 + q * 4);
      *(float4*)&cbs16[e][q*4] = v;
    }
    __syncthreads();
    {
      double pa0[16], pa1[16];
#pragma unroll
      for (int e = 0; e < 16; ++e) { pa0[e] = 0.0; pa1[e] = 0.0; }
      const int i0 = tid * 2;
      for (int l = 0; l < 64; l += 4) {
        const float4 w0 = *(const float4*)(d_w1 + (ll)i0 * 64 + l);
        const float4 w1 = *(const float4*)(d_w1 + (ll)(i0 + 1) * 64 + l);
#pragma unroll
        for (int e = 0; e < 16; ++e) {
          const float4 c4 = *(const float4*)&cbs16[e][l];
          pa0[e] = fma((double)w0.x,(double)c4.x, fma((double)w0.y,(double)c4.y,
                   fma((double)w0.z,(double)c4.z, fma((double)w0.w,(double)c4.w, pa0[e]))));
          pa1[e] = fma((double)w1.x,(double)c4.x, fma((double)w1.y,(double)c4.y,
                   fma((double)w1.z,(double)c4.z, fma((double)w1.w,(double)c4.w, pa1[e]))));
        }
      }
      const double db0 = (double)d_b1[i0], db1 = (double)d_b1[i0 + 1];
#pragma unroll
      for (int e = 0; e < 16; ++e) {
        pbuf[e][i0]     = (float)fmax(pa0[e] + db0, 0.0);
        pbuf[e][i0 + 1] = (float)fmax(pa1[e] + db1, 0.0);
      }
    }
    __syncthreads();
    {
      double ra[16][4];
#pragma unroll
      for (int e = 0; e < 16; ++e)
#pragma unroll
        for (int k = 0; k < 4; ++k) ra[e][k] = 0.0;
      const int o4 = tid * 4;
      for (int i4 = 0; i4 < 512; i4 += 4) {
        const float4 w0 = *(const float4*)(d_w2 + (ll)(o4+0) * 512 + i4);
        const float4 w1 = *(const float4*)(d_w2 + (ll)(o4+1) * 512 + i4);
        const float4 w2 = *(const float4*)(d_w2 + (ll)(o4+2) * 512 + i4);
        const float4 w3 = *(const float4*)(d_w2 + (ll)(o4+3) * 512 + i4);
#pragma unroll
        for (int e = 0; e < 16; ++e) {
          const float4 p4 = *(const float4*)&pbuf[e][i4];
          ra[e][0] = fma((double)w0.x,(double)p4.x, fma((double)w0.y,(double)p4.y,
                     fma((double)w0.z,(double)p4.z, fma((double)w0.w,(double)p4.w, ra[e][0]))));
          ra[e][1] = fma((double)w1.x,(double)p4.x, fma((double)w1.y,(double)p4.y,
                     fma((double)w1.z,(double)p4.z, fma((double)w1.w,(double)p4.w, ra[e][1]))));
          ra[e][2] = fma((double)w2.x,(double)p4.x, fma((double)w2.y,(double)p4.y,
                     fma((double)w2.z,(double)p4.z, fma((double)w2.w,(double)p4.w, ra[e][2]))));
          ra[e][3] = fma((double)w3.x,(double)p4.x, fma((double)w3.y,(double)p4.y,
                     fma((double)w3.z,(double)p4.z, fma((double)w3.w,(double)p4.w, ra[e][3]))));
        }
      }
      const float4 db = *(const float4*)(d_b2 + o4);
#pragma unroll
      for (int e = 0; e < 16; ++e) {
        *(float4*)(rect + (ll)(e0 + e) * 1024 + o4) =
          make_float4((float)(ra[e][0]+(double)db.x), (float)(ra[e][1]+(double)db.y),
                      (float)(ra[e][2]+(double)db.z), (float)(ra[e][3]+(double)db.w));
      }
    }
  } else {
    for (int k = tid; k < 2048; k += 256) {
      double s = 0.0;
      for (int l = 0; l < 64; ++l) {
        const float c = cbk[(ll)k * 64 + l];
        const float q = c * c;
        s += (double)q;
      }
      cnorm[k] = (float)s;
    }
  }
}

// =================== k_head (round 4 + conflict-reduced cbs assignment) ===================
__global__ __launch_bounds__(256)
void k_head(const float* __restrict__ rin, const float* __restrict__ e_w2,
            const float* __restrict__ e_b2, const float* __restrict__ cbk,
            const float* __restrict__ cnorm, const float* __restrict__ rect,
            float* __restrict__ dout, double* __restrict__ lossP)
{
  __shared__ float As[32][17];
  __shared__ float Bsh[16][68];
  __shared__ float hbuf[32][68];
  __shared__ float hA[32];
  __shared__ float cbs[128][68];
  __shared__ float cns[128];
  __shared__ float redv[32][33];
  __shared__ int   redi[32][33];
  __shared__ int   idxs[32];
  __shared__ double lred[256];
  const int tid = threadIdx.x;
  const int tx = tid & 31, ty = tid >> 5;
  const ll r0 = (ll)blockIdx.x * 32;

  // phase 1: h = fl(fl(r @ e_w2^T) + e_b2)
  double acc2[4][2];
#pragma unroll
  for (int i = 0; i < 4; ++i) { acc2[i][0] = 0.0; acc2[i][1] = 0.0; }
  for (int kc = 0; kc < 512; kc += 16) {
    if (tid < 128) {
      const int rr = tid >> 2, q = tid & 3;
      const float4 v = *(const float4*)(rin + (r0 + rr) * 512LL + kc + q * 4);
      As[rr][q*4+0] = v.x; As[rr][q*4+1] = v.y; As[rr][q*4+2] = v.z; As[rr][q*4+3] = v.w;
    }
    {
      const int c = tid >> 2, q = tid & 3;
      const float4 v = *(const float4*)(e_w2 + (ll)c * 512 + kc + q * 4);
      Bsh[q*4+0][c] = v.x; Bsh[q*4+1][c] = v.y; Bsh[q*4+2][c] = v.z; Bsh[q*4+3][c] = v.w;
    }
    __syncthreads();
#pragma unroll
    for (int j = 0; j < 16; ++j) {
      const double b0 = (double)Bsh[j][tx*2+0], b1 = (double)Bsh[j][tx*2+1];
      const double a0 = (double)As[ty*4+0][j], a1 = (double)As[ty*4+1][j];
      const double a2 = (double)As[ty*4+2][j], a3 = (double)As[ty*4+3][j];
      acc2[0][0] = fma(a0,b0,acc2[0][0]); acc2[0][1] = fma(a0,b1,acc2[0][1]);
      acc2[1][0] = fma(a1,b0,acc2[1][0]); acc2[1][1] = fma(a1,b1,acc2[1][1]);
      acc2[2][0] = fma(a2,b0,acc2[2][0]); acc2[2][1] = fma(a2,b1,acc2[2][1]);
      acc2[3][0] = fma(a3,b0,acc2[3][0]); acc2[3][1] = fma(a3,b1,acc2[3][1]);
    }
    __syncthreads();
  }
  {
    const float eb0 = e_b2[tx*2+0], eb1 = e_b2[tx*2+1];
#pragma unroll
    for (int i = 0; i < 4; ++i) {
      hbuf[ty*4+i][tx*2+0] = (float)acc2[i][0] + eb0;
      hbuf[ty*4+i][tx*2+1] = (float)acc2[i][1] + eb1;
    }
  }
  __syncthreads();

  // phase 1.5: A_row = fl(sum(fl(h^2)))
  if (tid < 32) {
    double s = 0.0;
    for (int l = 0; l < 64; ++l) {
      const float hh = hbuf[tid][l];
      const float q = hh * hh;
      s += (double)q;
    }
    hA[tid] = (float)s;
  }
  __syncthreads();

  // phase 2: dist = fl(fl(A + cn) - 2*fl(h.c)); argmin, first-index ties
  float bestv[4]; int besti[4];
#pragma unroll
  for (int i = 0; i < 4; ++i) { bestv[i] = 3.4e38f; besti[i] = 0; }
  for (int c0 = 0; c0 < 2048; c0 += 128) {
#pragma unroll
    for (int m = 0; m < 8; ++m) {
      const int l = m * 256 + tid;
      const int kk = l >> 4, q = l & 15;
      const float4 v = *(const float4*)(cbk + (ll)(c0 + kk) * 64 + q * 4);
      *(float4*)&cbs[kk][q*4] = v;
    }
    if (tid < 128) cns[tid] = cnorm[c0 + tid];
    __syncthreads();
    double dacc[4][4];
#pragma unroll
    for (int i = 0; i < 4; ++i)
#pragma unroll
      for (int j2 = 0; j2 < 4; ++j2) dacc[i][j2] = 0.0;
#pragma unroll
    for (int l = 0; l < 64; l += 4) {
      float4 ha[4], cv[4];
#pragma unroll
      for (int i = 0; i < 4; ++i) ha[i] = *(const float4*)&hbuf[ty*4+i][l];
#pragma unroll
      for (int j2 = 0; j2 < 4; ++j2) cv[j2] = *(const float4*)&cbs[tx + 32*j2][l];
#pragma unroll
      for (int i = 0; i < 4; ++i)
#pragma unroll
        for (int j2 = 0; j2 < 4; ++j2) {
          dacc[i][j2] = fma((double)ha[i].x, (double)cv[j2].x, dacc[i][j2]);
          dacc[i][j2] = fma((double)ha[i].y, (double)cv[j2].y, dacc[i][j2]);
          dacc[i][j2] = fma((double)ha[i].z, (double)cv[j2].z, dacc[i][j2]);
          dacc[i][j2] = fma((double)ha[i].w, (double)cv[j2].w, dacc[i][j2]);
        }
    }
#pragma unroll
    for (int i = 0; i < 4; ++i)
#pragma unroll
      for (int j2 = 0; j2 < 4; ++j2) {
        const float C32 = (float)dacc[i][j2];          // fl(h@c.T)
        const float D = 2.0f * C32;                    // exact x2
        const float E = hA[ty*4+i] + cns[tx + 32*j2];  // fl(A + cn)
        const float dist = E - D;                      // fl(E - D)
        const int kg = c0 + tx + 32*j2;
        if (dist < bestv[i]) { bestv[i] = dist; besti[i] = kg; }
      }
    __syncthreads();
  }
#pragma unroll
  for (int i = 0; i < 4; ++i) { redv[ty*4+i][tx] = bestv[i]; redi[ty*4+i][tx] = besti[i]; }
  __syncthreads();
  if (tid < 32) {
    float bv = redv[tid][0]; int bi = redi[tid][0];
    for (int x = 1; x < 32; ++x) {
      const float v = redv[tid][x]; const int ii = redi[tid][x];
      if (v < bv || (v == bv && ii < bi)) { bv = v; bi = ii; }
    }
    idxs[tid] = bi;
    dout[IDX_OFF + r0 + tid] = (float)bi;
  }
  __syncthreads();

  // phase 3: loss partials
  {
    const int r = tid >> 3, sl = tid & 7;
    const float* cq = cbk + (ll)idxs[r] * 64 + sl * 8;
    double s = 0.0;
#pragma unroll
    for (int e = 0; e < 8; ++e) {
      const float dx = cq[e] - hbuf[r][sl*8 + e];
      const float sq = dx * dx;
      s += (double)sq;
    }
    lred[tid] = s;
  }
  __syncthreads();
  for (int off = 128; off > 0; off >>= 1) {
    if (tid < off) lred[tid] += lred[tid + off];
    __syncthreads();
  }
  if (tid == 0) lossP[blockIdx.x] = lred[0];

  // phase 4: rec = rec_table[idx]
  for (int m = 0; m < 32; ++m) {
    const float4 v = *(const float4*)(rect + (ll)idxs[m] * 1024 + tid * 4);
    *(float4*)(dout + (r0 + m) * 1024 + tid * 4) = v;
  }
}

// =================== k_loss (verbatim round 4) ===================
__global__ __launch_bounds__(256)
void k_loss(const double* __restrict__ lossP, float* __restrict__ dout)
{
  __shared__ double red[256];
  const int tid = threadIdx.x;
  double s = 0.0;
  for (int i = tid; i < 2048; i += 256) s += lossP[i];
  red[tid] = s;
  __syncthreads();
  for (int off = 128; off > 0; off >>= 1) {
    if (tid < off) red[tid] += red[tid + off];
    __syncthreads();
  }
  if (tid == 0) {
    const float m1 = (float)(red[0] * (1.0 / 4194304.0));
    dout[LOSS_OFF] = m1 + 0.25f * m1;
  }
}

// =================== launch ===================
extern "C" void kernel_launch(void* const* d_in, const int* in_sizes, int n_in,
                              void* d_out, int out_size, void* d_ws, size_t ws_size,
                              hipStream_t stream)
{
  (void)in_sizes; (void)n_in; (void)out_size; (void)ws_size;
  const float* df    = (const float*)d_in[0];
  const float* tf    = (const float*)d_in[1];
  const float* dp_w  = (const float*)d_in[2];
  const float* dp_b  = (const float*)d_in[3];
  const float* tp_w  = (const float*)d_in[4];
  const float* tp_b  = (const float*)d_in[5];
  const float* in_w  = (const float*)d_in[6];
  const float* in_b  = (const float*)d_in[7];
  const float* out_w = (const float*)d_in[8];
  const float* out_b = (const float*)d_in[9];
  const float* n1w   = (const float*)d_in[10];
  const float* n1b   = (const float*)d_in[11];
  const float* n2w   = (const float*)d_in[12];
  const float* n2b   = (const float*)d_in[13];
  const float* e_w1  = (const float*)d_in[14];
  const float* e_b1  = (const float*)d_in[15];
  const float* e_lnw = (const float*)d_in[16];
  const float* e_lnb = (const float*)d_in[17];
  const float* e_w2  = (const float*)d_in[18];
  const float* e_b2  = (const float*)d_in[19];
  const float* cbk   = (const float*)d_in[20];
  const float* d_w1  = (const float*)d_in[21];
  const float* d_b1  = (const float*)d_in[22];
  const float* d_w2  = (const float*)d_in[23];
  const float* d_b2  = (const float*)d_in[24];
  float* out = (float*)d_out;
  float* ws  = (float*)d_ws;

  float* S0 = out;                  // d (raw), later rec overwrites
  float* S1 = out + BN * 512LL;     // lnd2 -> vh_d -> t2
  float* S2 = ws + WF_W1;           // t -> lnt1 -> vh_t -> d2 -> r
  float* RT = ws + WF_RT;
  float* CN = ws + WF_CN;
  double* LP = (double*)(ws + WF_LP);

  const float* wv = in_w + 1024LL * 512LL;
  const float* bv = in_b + 1024LL;

  k_pre<<<129, 256, 0, stream>>>(cbk, d_w1, d_b1, d_w2, d_b2, RT, CN);

  // d = fl(fl(df@dp_w^T)+dp_b) -> S0 ; lnd2 = LN(d, n2) -> S1   (mode 1)
  k_mm2<<<2048, 256, 0, stream>>>(df, nullptr, 48, dp_w, dp_b, nullptr,
                                  n2w, n2b, 1, S0, S1);
  // vh_d = fl(fl(lnd2@wv^T)+bv) -> S1 in-place   (mode 0)
  k_mm2<<<2048, 256, 0, stream>>>(S1, nullptr, 512, wv, bv, nullptr,
                                  nullptr, nullptr, 0, S1, nullptr);
  // t = fl(fl(tf@tp_w^T)+tp_b) -> S2   (mode 0)
  k_mm2<<<2048, 256, 0, stream>>>(tf, nullptr, 768, tp_w, tp_b, nullptr,
                                  nullptr, nullptr, 0, S2, nullptr);
  // t2 = fl(t + fl(fl(vh_d@out_w^T)+out_b)) -> S1 in-place, resid = t(S2)
  k_mm2<<<2048, 256, 0, stream>>>(S1, nullptr, 512, out_w, out_b, S2,
                                  nullptr, nullptr, 0, S1, nullptr);
  // lnt1 = LN(t, n1) -> S2 in-place (t dead)
  k_ln<<<16384, 256, 0, stream>>>(S2, n1w, n1b, S2, 0);
  // vh_t -> S2 in-place
  k_mm2<<<2048, 256, 0, stream>>>(S2, nullptr, 512, wv, bv, nullptr,
                                  nullptr, nullptr, 0, S2, nullptr);
  // d2 = fl(d + fl(fl(vh_t@out_w^T)+out_b)) -> S2 in-place, resid = d(S0)
  k_mm2<<<2048, 256, 0, stream>>>(S2, nullptr, 512, out_w, out_b, S0,
                                  nullptr, nullptr, 0, S2, nullptr);
  // u = fl(fl([d2|t2]@e_w1^T)+e_b1); r = relu(LN(u, e_ln)) -> S2 in-place  (mode 2)
  k_mm2<<<2048, 256, 0, stream>>>(S2, S1, 1024, e_w1, e_b1, nullptr,
                                  e_lnw, e_lnb, 2, S2, nullptr);
  // head + loss
  k_head<<<2048, 256, 0, stream>>>(S2, e_w2, e_b2, cbk, CN, RT, out, LP);
  k_loss<<<1, 256, 0, stream>>>(LP, out);
}

// Round 6
// 5688.208 us; speedup vs baseline: 2.0838x; 2.0838x over previous
//
#include <hip/hip_runtime.h>
#include <math.h>

typedef long long ll;
typedef double f64x4 __attribute__((ext_vector_type(4)));

#define BN 65536LL
#define LOSS_OFF (BN * 1024LL)
#define IDX_OFF  (LOSS_OFF + 1LL)

// ---- workspace layout (float offsets) ----
#define WF_W1 0LL                          // B x 512 scratch (ws slot S2)
#define WF_RT (WF_W1 + BN * 512LL)         // rec_table 2048 x 1024
#define WF_CN (WF_RT + 2048LL * 1024LL)    // cnorm 2048 (fp32)
#define WF_LP (WF_CN + 2048LL)             // loss partials 2048 doubles

#define BSTR 522   // B LDS row stride (f32): writes conflict-free, reads <=3-way

// =================== k_mmf: fp64-MFMA GEMM, Y = fl(fl(A@W^T)+b)[+resid], opt fused LN ===================
// 512 threads = 8 waves. Block tile: 32 rows x 512 cols. Wave: 16 rows x 128 cols
// (8 mfma_f64_16x16x4 fragments). fp64 accumulation via matrix pipe (harmless
// reassociation class); fp32 rounding at every np op boundary (proven round 4/5).
// MODE 0: raw -> Y.  MODE 1: raw -> Y, LN(raw) -> Y2.  MODE 2: relu(LN(raw)) -> Y.
template<int MODE>
__global__ __launch_bounds__(512, 4)
void k_mmf(const float* __restrict__ A0, const float* __restrict__ A1, int K,
           const float* __restrict__ W, const float* __restrict__ bias,
           const float* __restrict__ resid,
           const float* __restrict__ lnw, const float* __restrict__ lnb,
           float* __restrict__ Y, float* __restrict__ Y2)
{
  __shared__ double As64[16][33];          // [k][row], f64
  __shared__ double pool[4176];            // aliases: B f32 [16][522] | red dbl [32][65]
  __shared__ float msh[32], rsh[32];
  float* Bs = (float*)pool;
  double (*red)[65] = (double(*)[65])pool;

  const int tid = threadIdx.x;
  const int w = tid >> 6, l = tid & 63;
  const int q16 = l >> 4, l15 = l & 15;
  const int rbase = (w >> 2) * 16;         // wave's row half: 0 or 16
  const int cbase = (w & 3) * 128;         // wave's col quarter
  const ll r0 = (ll)blockIdx.x * 32;
  const int strideA0 = A1 ? 512 : K;

  f64x4 acc[8];
#pragma unroll
  for (int f = 0; f < 8; ++f) acc[f] = (f64x4){0.0, 0.0, 0.0, 0.0};

  for (int kc = 0; kc < K; kc += 16) {
    // stage A: 32 rows x 16 k (512 vals), thread t -> (row = t>>4, k = t&15)
    {
      const int row = tid >> 4, k = tid & 15;
      const int cidx = kc + k;
      float v;
      if (A1 && cidx >= 512) v = A1[(r0 + row) * 512LL + (cidx - 512)];
      else                   v = A0[(r0 + row) * (ll)strideA0 + cidx];
      As64[k][row] = (double)v;
    }
    // stage B: 16 k x 512 cols; slot s -> (col = s>>2, k-quad = s&3), float4 along k
#pragma unroll
    for (int m = 0; m < 4; ++m) {
      const int s = m * 512 + tid;
      const int col = s >> 2, kq = s & 3;
      const float4 v = *(const float4*)(W + (ll)col * K + kc + kq * 4);
      Bs[(kq*4+0)*BSTR + col] = v.x;
      Bs[(kq*4+1)*BSTR + col] = v.y;
      Bs[(kq*4+2)*BSTR + col] = v.z;
      Bs[(kq*4+3)*BSTR + col] = v.w;
    }
    __syncthreads();
#pragma unroll
    for (int kq = 0; kq < 4; ++kq) {
      const int kk = kq * 4 + q16;                    // lane's k: frag k = l>>4
      const double a = As64[kk][rbase + l15];         // A[row=l&15][k]
#pragma unroll
      for (int f = 0; f < 8; ++f) {
        const double b = (double)Bs[kk * BSTR + cbase + f*16 + l15]; // B[k][col=l&15]
        acc[f] = __builtin_amdgcn_mfma_f64_16x16x4f64(a, b, acc[f], 0, 0, 0);
      }
    }
    __syncthreads();
  }

  // epilogue: D layout row = rbase + 4*q16 + b, col = cbase + 16f + l15
  float o[8][4];
#pragma unroll
  for (int f = 0; f < 8; ++f)
#pragma unroll
    for (int b = 0; b < 4; ++b) {
      const int row = rbase + q16*4 + b;
      const int col = cbase + f*16 + l15;
      const float mm = (float)acc[f][b];   // fl(matmul)
      const float y1 = mm + bias[col];     // fl(+bias)
      o[f][b] = resid ? (resid[(r0 + row) * 512LL + col] + y1) : y1; // fl(resid+.)
    }

  if (MODE != 2) {
#pragma unroll
    for (int f = 0; f < 8; ++f)
#pragma unroll
      for (int b = 0; b < 4; ++b) {
        const int row = rbase + q16*4 + b;
        const int col = cbase + f*16 + l15;
        Y[(r0 + row) * 512LL + col] = o[f][b];
      }
  }
  if (MODE == 0) return;

  // fused LN (np-fp32 boundary chain, fp64 sums)
#pragma unroll
  for (int b = 0; b < 4; ++b) {
    double s = 0.0;
#pragma unroll
    for (int f = 0; f < 8; ++f) s += (double)o[f][b];
    red[rbase + q16*4 + b][(w & 3) * 16 + l15] = s;
  }
  __syncthreads();
  if (tid < 32) {
    double s = 0.0;
    for (int x = 0; x < 64; ++x) s += red[tid][x];
    msh[tid] = (float)(s * (1.0 / 512.0));
  }
  __syncthreads();
#pragma unroll
  for (int b = 0; b < 4; ++b) {
    const float m32 = msh[rbase + q16*4 + b];
    double s2 = 0.0;
#pragma unroll
    for (int f = 0; f < 8; ++f) {
      o[f][b] = o[f][b] - m32;                 // fp32 op (xm overwrites o)
      const float sq = o[f][b] * o[f][b];      // fp32 op
      s2 += (double)sq;
    }
    red[rbase + q16*4 + b][(w & 3) * 16 + l15] = s2;
  }
  __syncthreads();
  if (tid < 32) {
    double s = 0.0;
    for (int x = 0; x < 64; ++x) s += red[tid][x];
    const float v32 = (float)(s * (1.0 / 512.0));
    const float a32 = v32 + 1e-5f;
    const float sq32 = (float)sqrt((double)a32);   // CR fp32 sqrt
    rsh[tid] = (float)(1.0 / (double)sq32);        // CR fp32 div
  }
  __syncthreads();
  {
    float* dst = (MODE == 1) ? Y2 : Y;
#pragma unroll
    for (int b = 0; b < 4; ++b) {
      const float rs = rsh[rbase + q16*4 + b];
#pragma unroll
      for (int f = 0; f < 8; ++f) {
        const int row = rbase + q16*4 + b;
        const int col = cbase + f*16 + l15;
        float v = ((o[f][b] * rs) * lnw[col]) + lnb[col]; // fp32 chain
        if (MODE == 2) v = fmaxf(v, 0.f);
        dst[(r0 + row) * 512LL + col] = v;
      }
    }
  }
}

// =================== k_ln (verbatim passing version; used for lnt1) ===================
__global__ __launch_bounds__(256)
void k_ln(const float* __restrict__ X, const float* __restrict__ w,
          const float* __restrict__ b, float* __restrict__ Y, int relu)
{
  const int tid = threadIdx.x;
  const int lane = tid & 63, wid = tid >> 6;
  const ll row = (ll)blockIdx.x * 4 + wid;
  const ll base = row * 512;

  float xv[8];
#pragma unroll
  for (int j = 0; j < 8; ++j) xv[j] = X[base + j*64 + lane];

  double s = 0.0;
#pragma unroll
  for (int j = 0; j < 8; ++j) s += (double)xv[j];
#pragma unroll
  for (int off = 32; off > 0; off >>= 1) s += __shfl_down(s, off, 64);
  s = __shfl(s, 0, 64);
  const float m32 = (float)(s * (1.0 / 512.0));

  float xm[8];
  double s2 = 0.0;
#pragma unroll
  for (int j = 0; j < 8; ++j) {
    xm[j] = xv[j] - m32;
    const float sq = xm[j] * xm[j];
    s2 += (double)sq;
  }
#pragma unroll
  for (int off = 32; off > 0; off >>= 1) s2 += __shfl_down(s2, off, 64);
  s2 = __shfl(s2, 0, 64);
  const float v32 = (float)(s2 * (1.0 / 512.0));
  const float a32 = v32 + 1e-5f;
  const float sq32 = (float)sqrt((double)a32);
  const float rs32 = (float)(1.0 / (double)sq32);

#pragma unroll
  for (int j = 0; j < 8; ++j) {
    float o = ((xm[j] * rs32) * w[j*64 + lane]) + b[j*64 + lane];
    if (relu) o = fmaxf(o, 0.f);
    Y[base + j*64 + lane] = o;
  }
}

// =================== k_pre (verbatim passing version) ===================
__global__ __launch_bounds__(256)
void k_pre(const float* __restrict__ cbk, const float* __restrict__ d_w1,
           const float* __restrict__ d_b1, const float* __restrict__ d_w2,
           const float* __restrict__ d_b2,
           float* __restrict__ rect, float* __restrict__ cnorm)
{
  __shared__ float cbs16[16][68];
  __shared__ float pbuf[16][516];
  const int tid = threadIdx.x;
  const int bb = blockIdx.x;

  if (bb < 128) {
    const int e0 = bb * 16;
    {
      const int e = tid >> 4, q = tid & 15;
      const float4 v = *(const float4*)(cbk + (ll)(e0 + e) * 64 + q * 4);
      *(float4*)&cbs16[e][q*4] = v;
    }
    __syncthreads();
    {
      double pa0[16], pa1[16];
#pragma unroll
      for (int e = 0; e < 16; ++e) { pa0[e] = 0.0; pa1[e] = 0.0; }
      const int i0 = tid * 2;
      for (int l = 0; l < 64; l += 4) {
        const float4 w0 = *(const float4*)(d_w1 + (ll)i0 * 64 + l);
        const float4 w1 = *(const float4*)(d_w1 + (ll)(i0 + 1) * 64 + l);
#pragma unroll
        for (int e = 0; e < 16; ++e) {
          const float4 c4 = *(const float4*)&cbs16[e][l];
          pa0[e] = fma((double)w0.x,(double)c4.x, fma((double)w0.y,(double)c4.y,
                   fma((double)w0.z,(double)c4.z, fma((double)w0.w,(double)c4.w, pa0[e]))));
          pa1[e] = fma((double)w1.x,(double)c4.x, fma((double)w1.y,(double)c4.y,
                   fma((double)w1.z,(double)c4.z, fma((double)w1.w,(double)c4.w, pa1[e]))));
        }
      }
      const double db0 = (double)d_b1[i0], db1 = (double)d_b1[i0 + 1];
#pragma unroll
      for (int e = 0; e < 16; ++e) {
        pbuf[e][i0]     = (float)fmax(pa0[e] + db0, 0.0);
        pbuf[e][i0 + 1] = (float)fmax(pa1[e] + db1, 0.0);
      }
    }
    __syncthreads();
    {
      double ra[16][4];
#pragma unroll
      for (int e = 0; e < 16; ++e)
#pragma unroll
        for (int k = 0; k < 4; ++k) ra[e][k] = 0.0;
      const int o4 = tid * 4;
      for (int i4 = 0; i4 < 512; i4 += 4) {
        const float4 w0 = *(const float4*)(d_w2 + (ll)(o4+0) * 512 + i4);
        const float4 w1 = *(const float4*)(d_w2 + (ll)(o4+1) * 512 + i4);
        const float4 w2 = *(const float4*)(d_w2 + (ll)(o4+2) * 512 + i4);
        const float4 w3 = *(const float4*)(d_w2 + (ll)(o4+3) * 512 + i4);
#pragma unroll
        for (int e = 0; e < 16; ++e) {
          const float4 p4 = *(const float4*)&pbuf[e][i4];
          ra[e][0] = fma((double)w0.x,(double)p4.x, fma((double)w0.y,(double)p4.y,
                     fma((double)w0.z,(double)p4.z, fma((double)w0.w,(double)p4.w, ra[e][0]))));
          ra[e][1] = fma((double)w1.x,(double)p4.x, fma((double)w1.y,(double)p4.y,
                     fma((double)w1.z,(double)p4.z, fma((double)w1.w,(double)p4.w, ra[e][1]))));
          ra[e][2] = fma((double)w2.x,(double)p4.x, fma((double)w2.y,(double)p4.y,
                     fma((double)w2.z,(double)p4.z, fma((double)w2.w,(double)p4.w, ra[e][2]))));
          ra[e][3] = fma((double)w3.x,(double)p4.x, fma((double)w3.y,(double)p4.y,
                     fma((double)w3.z,(double)p4.z, fma((double)w3.w,(double)p4.w, ra[e][3]))));
        }
      }
      const float4 db = *(const float4*)(d_b2 + o4);
#pragma unroll
      for (int e = 0; e < 16; ++e) {
        *(float4*)(rect + (ll)(e0 + e) * 1024 + o4) =
          make_float4((float)(ra[e][0]+(double)db.x), (float)(ra[e][1]+(double)db.y),
                      (float)(ra[e][2]+(double)db.z), (float)(ra[e][3]+(double)db.w));
      }
    }
  } else {
    for (int k = tid; k < 2048; k += 256) {
      double s = 0.0;
      for (int l = 0; l < 64; ++l) {
        const float c = cbk[(ll)k * 64 + l];
        const float q = c * c;
        s += (double)q;
      }
      cnorm[k] = (float)s;
    }
  }
}

// =================== k_head (verbatim passing version) ===================
__global__ __launch_bounds__(256)
void k_head(const float* __restrict__ rin, const float* __restrict__ e_w2,
            const float* __restrict__ e_b2, const float* __restrict__ cbk,
            const float* __restrict__ cnorm, const float* __restrict__ rect,
            float* __restrict__ dout, double* __restrict__ lossP)
{
  __shared__ float As[32][17];
  __shared__ float Bsh[16][68];
  __shared__ float hbuf[32][68];
  __shared__ float hA[32];
  __shared__ float cbs[128][68];
  __shared__ float cns[128];
  __shared__ float redv[32][33];
  __shared__ int   redi[32][33];
  __shared__ int   idxs[32];
  __shared__ double lred[256];
  const int tid = threadIdx.x;
  const int tx = tid & 31, ty = tid >> 5;
  const ll r0 = (ll)blockIdx.x * 32;

  double acc2[4][2];
#pragma unroll
  for (int i = 0; i < 4; ++i) { acc2[i][0] = 0.0; acc2[i][1] = 0.0; }
  for (int kc = 0; kc < 512; kc += 16) {
    if (tid < 128) {
      const int rr = tid >> 2, q = tid & 3;
      const float4 v = *(const float4*)(rin + (r0 + rr) * 512LL + kc + q * 4);
      As[rr][q*4+0] = v.x; As[rr][q*4+1] = v.y; As[rr][q*4+2] = v.z; As[rr][q*4+3] = v.w;
    }
    {
      const int c = tid >> 2, q = tid & 3;
      const float4 v = *(const float4*)(e_w2 + (ll)c * 512 + kc + q * 4);
      Bsh[q*4+0][c] = v.x; Bsh[q*4+1][c] = v.y; Bsh[q*4+2][c] = v.z; Bsh[q*4+3][c] = v.w;
    }
    __syncthreads();
#pragma unroll
    for (int j = 0; j < 16; ++j) {
      const double b0 = (double)Bsh[j][tx*2+0], b1 = (double)Bsh[j][tx*2+1];
      const double a0 = (double)As[ty*4+0][j], a1 = (double)As[ty*4+1][j];
      const double a2 = (double)As[ty*4+2][j], a3 = (double)As[ty*4+3][j];
      acc2[0][0] = fma(a0,b0,acc2[0][0]); acc2[0][1] = fma(a0,b1,acc2[0][1]);
      acc2[1][0] = fma(a1,b0,acc2[1][0]); acc2[1][1] = fma(a1,b1,acc2[1][1]);
      acc2[2][0] = fma(a2,b0,acc2[2][0]); acc2[2][1] = fma(a2,b1,acc2[2][1]);
      acc2[3][0] = fma(a3,b0,acc2[3][0]); acc2[3][1] = fma(a3,b1,acc2[3][1]);
    }
    __syncthreads();
  }
  {
    const float eb0 = e_b2[tx*2+0], eb1 = e_b2[tx*2+1];
#pragma unroll
    for (int i = 0; i < 4; ++i) {
      hbuf[ty*4+i][tx*2+0] = (float)acc2[i][0] + eb0;
      hbuf[ty*4+i][tx*2+1] = (float)acc2[i][1] + eb1;
    }
  }
  __syncthreads();

  if (tid < 32) {
    double s = 0.0;
    for (int l = 0; l < 64; ++l) {
      const float hh = hbuf[tid][l];
      const float q = hh * hh;
      s += (double)q;
    }
    hA[tid] = (float)s;
  }
  __syncthreads();

  float bestv[4]; int besti[4];
#pragma unroll
  for (int i = 0; i < 4; ++i) { bestv[i] = 3.4e38f; besti[i] = 0; }
  for (int c0 = 0; c0 < 2048; c0 += 128) {
#pragma unroll
    for (int m = 0; m < 8; ++m) {
      const int l = m * 256 + tid;
      const int kk = l >> 4, q = l & 15;
      const float4 v = *(const float4*)(cbk + (ll)(c0 + kk) * 64 + q * 4);
      *(float4*)&cbs[kk][q*4] = v;
    }
    if (tid < 128) cns[tid] = cnorm[c0 + tid];
    __syncthreads();
    double dacc[4][4];
#pragma unroll
    for (int i = 0; i < 4; ++i)
#pragma unroll
      for (int j2 = 0; j2 < 4; ++j2) dacc[i][j2] = 0.0;
#pragma unroll
    for (int l = 0; l < 64; l += 4) {
      float4 ha[4], cv[4];
#pragma unroll
      for (int i = 0; i < 4; ++i) ha[i] = *(const float4*)&hbuf[ty*4+i][l];
#pragma unroll
      for (int j2 = 0; j2 < 4; ++j2) cv[j2] = *(const float4*)&cbs[tx + 32*j2][l];
#pragma unroll
      for (int i = 0; i < 4; ++i)
#pragma unroll
        for (int j2 = 0; j2 < 4; ++j2) {
          dacc[i][j2] = fma((double)ha[i].x, (double)cv[j2].x, dacc[i][j2]);
          dacc[i][j2] = fma((double)ha[i].y, (double)cv[j2].y, dacc[i][j2]);
          dacc[i][j2] = fma((double)ha[i].z, (double)cv[j2].z, dacc[i][j2]);
          dacc[i][j2] = fma((double)ha[i].w, (double)cv[j2].w, dacc[i][j2]);
        }
    }
#pragma unroll
    for (int i = 0; i < 4; ++i)
#pragma unroll
      for (int j2 = 0; j2 < 4; ++j2) {
        const float C32 = (float)dacc[i][j2];
        const float D = 2.0f * C32;
        const float E = hA[ty*4+i] + cns[tx + 32*j2];
        const float dist = E - D;
        const int kg = c0 + tx + 32*j2;
        if (dist < bestv[i]) { bestv[i] = dist; besti[i] = kg; }
      }
    __syncthreads();
  }
#pragma unroll
  for (int i = 0; i < 4; ++i) { redv[ty*4+i][tx] = bestv[i]; redi[ty*4+i][tx] = besti[i]; }
  __syncthreads();
  if (tid < 32) {
    float bv = redv[tid][0]; int bi = redi[tid][0];
    for (int x = 1; x < 32; ++x) {
      const float v = redv[tid][x]; const int ii = redi[tid][x];
      if (v < bv || (v == bv && ii < bi)) { bv = v; bi = ii; }
    }
    idxs[tid] = bi;
    dout[IDX_OFF + r0 + tid] = (float)bi;
  }
  __syncthreads();

  {
    const int r = tid >> 3, sl = tid & 7;
    const float* cq = cbk + (ll)idxs[r] * 64 + sl * 8;
    double s = 0.0;
#pragma unroll
    for (int e = 0; e < 8; ++e) {
      const float dx = cq[e] - hbuf[r][sl*8 + e];
      const float sq = dx * dx;
      s += (double)sq;
    }
    lred[tid] = s;
  }
  __syncthreads();
  for (int off = 128; off > 0; off >>= 1) {
    if (tid < off) lred[tid] += lred[tid + off];
    __syncthreads();
  }
  if (tid == 0) lossP[blockIdx.x] = lred[0];

  for (int m = 0; m < 32; ++m) {
    const float4 v = *(const float4*)(rect + (ll)idxs[m] * 1024 + tid * 4);
    *(float4*)(dout + (r0 + m) * 1024 + tid * 4) = v;
  }
}

// =================== k_loss (verbatim passing version) ===================
__global__ __launch_bounds__(256)
void k_loss(const double* __restrict__ lossP, float* __restrict__ dout)
{
  __shared__ double red[256];
  const int tid = threadIdx.x;
  double s = 0.0;
  for (int i = tid; i < 2048; i += 256) s += lossP[i];
  red[tid] = s;
  __syncthreads();
  for (int off = 128; off > 0; off >>= 1) {
    if (tid < off) red[tid] += red[tid + off];
    __syncthreads();
  }
  if (tid == 0) {
    const float m1 = (float)(red[0] * (1.0 / 4194304.0));
    dout[LOSS_OFF] = m1 + 0.25f * m1;
  }
}

// =================== launch ===================
extern "C" void kernel_launch(void* const* d_in, const int* in_sizes, int n_in,
                              void* d_out, int out_size, void* d_ws, size_t ws_size,
                              hipStream_t stream)
{
  (void)in_sizes; (void)n_in; (void)out_size; (void)ws_size;
  const float* df    = (const float*)d_in[0];
  const float* tf    = (const float*)d_in[1];
  const float* dp_w  = (const float*)d_in[2];
  const float* dp_b  = (const float*)d_in[3];
  const float* tp_w  = (const float*)d_in[4];
  const float* tp_b  = (const float*)d_in[5];
  const float* in_w  = (const float*)d_in[6];
  const float* in_b  = (const float*)d_in[7];
  const float* out_w = (const float*)d_in[8];
  const float* out_b = (const float*)d_in[9];
  const float* n1w   = (const float*)d_in[10];
  const float* n1b   = (const float*)d_in[11];
  const float* n2w   = (const float*)d_in[12];
  const float* n2b   = (const float*)d_in[13];
  const float* e_w1  = (const float*)d_in[14];
  const float* e_b1  = (const float*)d_in[15];
  const float* e_lnw = (const float*)d_in[16];
  const float* e_lnb = (const float*)d_in[17];
  const float* e_w2  = (const float*)d_in[18];
  const float* e_b2  = (const float*)d_in[19];
  const float* cbk   = (const float*)d_in[20];
  const float* d_w1  = (const float*)d_in[21];
  const float* d_b1  = (const float*)d_in[22];
  const float* d_w2  = (const float*)d_in[23];
  const float* d_b2  = (const float*)d_in[24];
  float* out = (float*)d_out;
  float* ws  = (float*)d_ws;

  float* S0 = out;                  // d (raw), later rec overwrites
  float* S1 = out + BN * 512LL;     // lnd2 -> vh_d -> t2
  float* S2 = ws + WF_W1;           // t -> lnt1 -> vh_t -> d2 -> r
  float* RT = ws + WF_RT;
  float* CN = ws + WF_CN;
  double* LP = (double*)(ws + WF_LP);

  const float* wv = in_w + 1024LL * 512LL;
  const float* bv = in_b + 1024LL;

  k_pre<<<129, 256, 0, stream>>>(cbk, d_w1, d_b1, d_w2, d_b2, RT, CN);

  // d = fl(fl(df@dp_w^T)+dp_b) -> S0 ; lnd2 = LN(d, n2) -> S1   (mode 1)
  k_mmf<1><<<2048, 512, 0, stream>>>(df, nullptr, 48, dp_w, dp_b, nullptr,
                                     n2w, n2b, S0, S1);
  // vh_d = fl(fl(lnd2@wv^T)+bv) -> S1 in-place   (mode 0)
  k_mmf<0><<<2048, 512, 0, stream>>>(S1, nullptr, 512, wv, bv, nullptr,
                                     nullptr, nullptr, S1, nullptr);
  // t = fl(fl(tf@tp_w^T)+tp_b) -> S2   (mode 0)
  k_mmf<0><<<2048, 512, 0, stream>>>(tf, nullptr, 768, tp_w, tp_b, nullptr,
                                     nullptr, nullptr, S2, nullptr);
  // t2 = fl(t + fl(fl(vh_d@out_w^T)+out_b)) -> S1 in-place, resid = t(S2)
  k_mmf<0><<<2048, 512, 0, stream>>>(S1, nullptr, 512, out_w, out_b, S2,
                                     nullptr, nullptr, S1, nullptr);
  // lnt1 = LN(t, n1) -> S2 in-place (t dead)
  k_ln<<<16384, 256, 0, stream>>>(S2, n1w, n1b, S2, 0);
  // vh_t -> S2 in-place
  k_mmf<0><<<2048, 512, 0, stream>>>(S2, nullptr, 512, wv, bv, nullptr,
                                     nullptr, nullptr, S2, nullptr);
  // d2 = fl(d + fl(fl(vh_t@out_w^T)+out_b)) -> S2 in-place, resid = d(S0)
  k_mmf<0><<<2048, 512, 0, stream>>>(S2, nullptr, 512, out_w, out_b, S0,
                                     nullptr, nullptr, S2, nullptr);
  // u = fl(fl([d2|t2]@e_w1^T)+e_b1); r = relu(LN(u, e_ln)) -> S2 in-place  (mode 2)
  k_mmf<2><<<2048, 512, 0, stream>>>(S2, S1, 1024, e_w1, e_b1, nullptr,
                                     e_lnw, e_lnb, S2, nullptr);
  // head + loss
  k_head<<<2048, 256, 0, stream>>>(S2, e_w2, e_b2, cbk, CN, RT, out, LP);
  k_loss<<<1, 256, 0, stream>>>(LP, out);
}

// Round 8
// 5201.552 us; speedup vs baseline: 2.2788x; 1.0936x over previous
//
#include <hip/hip_runtime.h>
#include <math.h>

typedef long long ll;
typedef double f64x4 __attribute__((ext_vector_type(4)));

#define BN 65536LL
#define LOSS_OFF (BN * 1024LL)
#define IDX_OFF  (LOSS_OFF + 1LL)

// ---- workspace layout (float offsets) ----
#define WF_W1 0LL                          // B x 512 scratch (ws slot S2)
#define WF_RT (WF_W1 + BN * 512LL)         // rec_table 2048 x 1024
#define WF_CN (WF_RT + 2048LL * 1024LL)    // cnorm 2048 (fp32)
#define WF_LP (WF_CN + 2048LL)             // loss partials 2048 doubles

#define BSTR 522   // B LDS row stride (f32)

// =================== k_mmf: fp64-MFMA GEMM, double-buffered LDS ===================
// 512 threads = 8 waves. Block tile: 32 rows x 512 cols. Wave: 16 rows x 128 cols
// (8 mfma_f64_16x16x4). Bit-identical MFMA sequence to the round-6 passing kernel
// (same kc -> kq -> f order, same operands); double-buffering changes scheduling only.
// MODE 0: raw -> Y.  MODE 1: raw -> Y, LN(raw) -> Y2.  MODE 2: relu(LN(raw)) -> Y.
template<int MODE>
__global__ __launch_bounds__(512, 4)
void k_mmf(const float* __restrict__ A0, const float* __restrict__ A1, int K,
           const float* __restrict__ W, const float* __restrict__ bias,
           const float* __restrict__ resid,
           const float* __restrict__ lnw, const float* __restrict__ lnb,
           float* __restrict__ Y, float* __restrict__ Y2)
{
  __shared__ double As64[2][16][33];       // [buf][k][row] f64
  __shared__ double poolB[2][4176];        // [buf] 16 x 522 f32
  __shared__ float msh[32], rsh[32];
  double (*red)[65] = (double(*)[65])poolB[0];  // aliased post-loop (safe: after final barrier)

  const int tid = threadIdx.x;
  const int w = tid >> 6, l = tid & 63;
  const int q16 = l >> 4, l15 = l & 15;
  const int rbase = (w >> 2) * 16;         // wave row half
  const int cbase = (w & 3) * 128;         // wave col quarter
  const ll r0 = (ll)blockIdx.x * 32;
  const int strideA0 = A1 ? 512 : K;
  const int arow = tid >> 4, ak = tid & 15;

  f64x4 acc[8];
#pragma unroll
  for (int f = 0; f < 8; ++f) acc[f] = (f64x4){0.0, 0.0, 0.0, 0.0};

  // ---- prologue: stage kc=0 into buf 0 ----
  {
    float av = A0[(r0 + arow) * (ll)strideA0 + ak];   // ak < 16 < 512: always A0
    float4 bv4[4];
#pragma unroll
    for (int m = 0; m < 4; ++m) {
      const int s = m * 512 + tid;
      const int col = s >> 2, kq = s & 3;
      bv4[m] = *(const float4*)(W + (ll)col * K + kq * 4);
    }
    As64[0][ak][arow] = (double)av;
    float* B0 = (float*)poolB[0];
#pragma unroll
    for (int m = 0; m < 4; ++m) {
      const int s = m * 512 + tid;
      const int col = s >> 2, kq = s & 3;
      B0[(kq*4+0)*BSTR + col] = bv4[m].x;
      B0[(kq*4+1)*BSTR + col] = bv4[m].y;
      B0[(kq*4+2)*BSTR + col] = bv4[m].z;
      B0[(kq*4+3)*BSTR + col] = bv4[m].w;
    }
  }
  __syncthreads();

  int cur = 0;
  for (int kc = 0; kc < K; kc += 16) {
    const bool more = (kc + 16) < K;
    float av; float4 bv4[4];
    if (more) {                            // issue next-step loads EARLY
      const int cidx = kc + 16 + ak;
      if (A1 && cidx >= 512) av = A1[(r0 + arow) * 512LL + (cidx - 512)];
      else                   av = A0[(r0 + arow) * (ll)strideA0 + cidx];
#pragma unroll
      for (int m = 0; m < 4; ++m) {
        const int s = m * 512 + tid;
        const int col = s >> 2, kq = s & 3;
        bv4[m] = *(const float4*)(W + (ll)col * K + kc + 16 + kq * 4);
      }
    }
    // MFMA on current buffer (identical order to round 6)
    {
      const double (*A_)[33] = As64[cur];
      const float* B_ = (const float*)poolB[cur];
#pragma unroll
      for (int kq = 0; kq < 4; ++kq) {
        const int kk = kq * 4 + q16;
        const double a = A_[kk][rbase + l15];
#pragma unroll
        for (int f = 0; f < 8; ++f) {
          const double b = (double)B_[kk * BSTR + cbase + f*16 + l15];
          acc[f] = __builtin_amdgcn_mfma_f64_16x16x4f64(a, b, acc[f], 0, 0, 0);
        }
      }
    }
    if (more) {                            // write-late into next buffer
      As64[cur ^ 1][ak][arow] = (double)av;
      float* Bn = (float*)poolB[cur ^ 1];
#pragma unroll
      for (int m = 0; m < 4; ++m) {
        const int s = m * 512 + tid;
        const int col = s >> 2, kq = s & 3;
        Bn[(kq*4+0)*BSTR + col] = bv4[m].x;
        Bn[(kq*4+1)*BSTR + col] = bv4[m].y;
        Bn[(kq*4+2)*BSTR + col] = bv4[m].z;
        Bn[(kq*4+3)*BSTR + col] = bv4[m].w;
      }
    }
    __syncthreads();
    cur ^= 1;
  }

  // epilogue: D layout row = rbase + 4*q16 + b, col = cbase + 16f + l15
  float o[8][4];
#pragma unroll
  for (int f = 0; f < 8; ++f)
#pragma unroll
    for (int b = 0; b < 4; ++b) {
      const int row = rbase + q16*4 + b;
      const int col = cbase + f*16 + l15;
      const float mm = (float)acc[f][b];   // fl(matmul)
      const float y1 = mm + bias[col];     // fl(+bias)
      o[f][b] = resid ? (resid[(r0 + row) * 512LL + col] + y1) : y1; // fl(resid+.)
    }

  if (MODE != 2) {
#pragma unroll
    for (int f = 0; f < 8; ++f)
#pragma unroll
      for (int b = 0; b < 4; ++b) {
        const int row = rbase + q16*4 + b;
        const int col = cbase + f*16 + l15;
        Y[(r0 + row) * 512LL + col] = o[f][b];
      }
  }
  if (MODE == 0) return;

  // fused LN (np-fp32 boundary chain, fp64 sums)
#pragma unroll
  for (int b = 0; b < 4; ++b) {
    double s = 0.0;
#pragma unroll
    for (int f = 0; f < 8; ++f) s += (double)o[f][b];
    red[rbase + q16*4 + b][(w & 3) * 16 + l15] = s;
  }
  __syncthreads();
  if (tid < 32) {
    double s = 0.0;
    for (int x = 0; x < 64; ++x) s += red[tid][x];
    msh[tid] = (float)(s * (1.0 / 512.0));
  }
  __syncthreads();
#pragma unroll
  for (int b = 0; b < 4; ++b) {
    const float m32 = msh[rbase + q16*4 + b];
    double s2 = 0.0;
#pragma unroll
    for (int f = 0; f < 8; ++f) {
      o[f][b] = o[f][b] - m32;                 // fp32 op
      const float sq = o[f][b] * o[f][b];      // fp32 op
      s2 += (double)sq;
    }
    red[rbase + q16*4 + b][(w & 3) * 16 + l15] = s2;
  }
  __syncthreads();
  if (tid < 32) {
    double s = 0.0;
    for (int x = 0; x < 64; ++x) s += red[tid][x];
    const float v32 = (float)(s * (1.0 / 512.0));
    const float a32 = v32 + 1e-5f;
    const float sq32 = (float)sqrt((double)a32);   // CR fp32 sqrt
    rsh[tid] = (float)(1.0 / (double)sq32);        // CR fp32 div
  }
  __syncthreads();
  {
    float* dst = (MODE == 1) ? Y2 : Y;
#pragma unroll
    for (int b = 0; b < 4; ++b) {
      const float rs = rsh[rbase + q16*4 + b];
#pragma unroll
      for (int f = 0; f < 8; ++f) {
        const int row = rbase + q16*4 + b;
        const int col = cbase + f*16 + l15;
        float v = ((o[f][b] * rs) * lnw[col]) + lnb[col]; // fp32 chain
        if (MODE == 2) v = fmaxf(v, 0.f);
        dst[(r0 + row) * 512LL + col] = v;
      }
    }
  }
}

// =================== k_ln (verbatim round-6 passing version) ===================
__global__ __launch_bounds__(256)
void k_ln(const float* __restrict__ X, const float* __restrict__ w,
          const float* __restrict__ b, float* __restrict__ Y, int relu)
{
  const int tid = threadIdx.x;
  const int lane = tid & 63, wid = tid >> 6;
  const ll row = (ll)blockIdx.x * 4 + wid;
  const ll base = row * 512;

  float xv[8];
#pragma unroll
  for (int j = 0; j < 8; ++j) xv[j] = X[base + j*64 + lane];

  double s = 0.0;
#pragma unroll
  for (int j = 0; j < 8; ++j) s += (double)xv[j];
#pragma unroll
  for (int off = 32; off > 0; off >>= 1) s += __shfl_down(s, off, 64);
  s = __shfl(s, 0, 64);
  const float m32 = (float)(s * (1.0 / 512.0));

  float xm[8];
  double s2 = 0.0;
#pragma unroll
  for (int j = 0; j < 8; ++j) {
    xm[j] = xv[j] - m32;
    const float sq = xm[j] * xm[j];
    s2 += (double)sq;
  }
#pragma unroll
  for (int off = 32; off > 0; off >>= 1) s2 += __shfl_down(s2, off, 64);
  s2 = __shfl(s2, 0, 64);
  const float v32 = (float)(s2 * (1.0 / 512.0));
  const float a32 = v32 + 1e-5f;
  const float sq32 = (float)sqrt((double)a32);
  const float rs32 = (float)(1.0 / (double)sq32);

#pragma unroll
  for (int j = 0; j < 8; ++j) {
    float o = ((xm[j] * rs32) * w[j*64 + lane]) + b[j*64 + lane];
    if (relu) o = fmaxf(o, 0.f);
    Y[base + j*64 + lane] = o;
  }
}

// =================== k_pre (verbatim round-6 passing version) ===================
__global__ __launch_bounds__(256)
void k_pre(const float* __restrict__ cbk, const float* __restrict__ d_w1,
           const float* __restrict__ d_b1, const float* __restrict__ d_w2,
           const float* __restrict__ d_b2,
           float* __restrict__ rect, float* __restrict__ cnorm)
{
  __shared__ float cbs16[16][68];
  __shared__ float pbuf[16][516];
  const int tid = threadIdx.x;
  const int bb = blockIdx.x;

  if (bb < 128) {
    const int e0 = bb * 16;
    {
      const int e = tid >> 4, q = tid & 15;
      const float4 v = *(const float4*)(cbk + (ll)(e0 + e) * 64 + q * 4);
      *(float4*)&cbs16[e][q*4] = v;
    }
    __syncthreads();
    {
      double pa0[16], pa1[16];
#pragma unroll
      for (int e = 0; e < 16; ++e) { pa0[e] = 0.0; pa1[e] = 0.0; }
      const int i0 = tid * 2;
      for (int l = 0; l < 64; l += 4) {
        const float4 w0 = *(const float4*)(d_w1 + (ll)i0 * 64 + l);
        const float4 w1 = *(const float4*)(d_w1 + (ll)(i0 + 1) * 64 + l);
#pragma unroll
        for (int e = 0; e < 16; ++e) {
          const float4 c4 = *(const float4*)&cbs16[e][l];
          pa0[e] = fma((double)w0.x,(double)c4.x, fma((double)w0.y,(double)c4.y,
                   fma((double)w0.z,(double)c4.z, fma((double)w0.w,(double)c4.w, pa0[e]))));
          pa1[e] = fma((double)w1.x,(double)c4.x, fma((double)w1.y,(double)c4.y,
                   fma((double)w1.z,(double)c4.z, fma((double)w1.w,(double)c4.w, pa1[e]))));
        }
      }
      const double db0 = (double)d_b1[i0], db1 = (double)d_b1[i0 + 1];
#pragma unroll
      for (int e = 0; e < 16; ++e) {
        pbuf[e][i0]     = (float)fmax(pa0[e] + db0, 0.0);
        pbuf[e][i0 + 1] = (float)fmax(pa1[e] + db1, 0.0);
      }
    }
    __syncthreads();
    {
      double ra[16][4];
#pragma unroll
      for (int e = 0; e < 16; ++e)
#pragma unroll
        for (int k = 0; k < 4; ++k) ra[e][k] = 0.0;
      const int o4 = tid * 4;
      for (int i4 = 0; i4 < 512; i4 += 4) {
        const float4 w0 = *(const float4*)(d_w2 + (ll)(o4+0) * 512 + i4);
        const float4 w1 = *(const float4*)(d_w2 + (ll)(o4+1) * 512 + i4);
        const float4 w2 = *(const float4*)(d_w2 + (ll)(o4+2) * 512 + i4);
        const float4 w3 = *(const float4*)(d_w2 + (ll)(o4+3) * 512 + i4);
#pragma unroll
        for (int e = 0; e < 16; ++e) {
          const float4 p4 = *(const float4*)&pbuf[e][i4];
          ra[e][0] = fma((double)w0.x,(double)p4.x, fma((double)w0.y,(double)p4.y,
                     fma((double)w0.z,(double)p4.z, fma((double)w0.w,(double)p4.w, ra[e][0]))));
          ra[e][1] = fma((double)w1.x,(double)p4.x, fma((double)w1.y,(double)p4.y,
                     fma((double)w1.z,(double)p4.z, fma((double)w1.w,(double)p4.w, ra[e][1]))));
          ra[e][2] = fma((double)w2.x,(double)p4.x, fma((double)w2.y,(double)p4.y,
                     fma((double)w2.z,(double)p4.z, fma((double)w2.w,(double)p4.w, ra[e][2]))));
          ra[e][3] = fma((double)w3.x,(double)p4.x, fma((double)w3.y,(double)p4.y,
                     fma((double)w3.z,(double)p4.z, fma((double)w3.w,(double)p4.w, ra[e][3]))));
        }
      }
      const float4 db = *(const float4*)(d_b2 + o4);
#pragma unroll
      for (int e = 0; e < 16; ++e) {
        *(float4*)(rect + (ll)(e0 + e) * 1024 + o4) =
          make_float4((float)(ra[e][0]+(double)db.x), (float)(ra[e][1]+(double)db.y),
                      (float)(ra[e][2]+(double)db.z), (float)(ra[e][3]+(double)db.w));
      }
    }
  } else {
    for (int k = tid; k < 2048; k += 256) {
      double s = 0.0;
      for (int l = 0; l < 64; ++l) {
        const float c = cbk[(ll)k * 64 + l];
        const float q = c * c;
        s += (double)q;
      }
      cnorm[k] = (float)s;
    }
  }
}

// =================== k_head (verbatim round-6 passing version: vector dist) ===================
__global__ __launch_bounds__(256)
void k_head(const float* __restrict__ rin, const float* __restrict__ e_w2,
            const float* __restrict__ e_b2, const float* __restrict__ cbk,
            const float* __restrict__ cnorm, const float* __restrict__ rect,
            float* __restrict__ dout, double* __restrict__ lossP)
{
  __shared__ float As[32][17];
  __shared__ float Bsh[16][68];
  __shared__ float hbuf[32][68];
  __shared__ float hA[32];
  __shared__ float cbs[128][68];
  __shared__ float cns[128];
  __shared__ float redv[32][33];
  __shared__ int   redi[32][33];
  __shared__ int   idxs[32];
  __shared__ double lred[256];
  const int tid = threadIdx.x;
  const int tx = tid & 31, ty = tid >> 5;
  const ll r0 = (ll)blockIdx.x * 32;

  double acc2[4][2];
#pragma unroll
  for (int i = 0; i < 4; ++i) { acc2[i][0] = 0.0; acc2[i][1] = 0.0; }
  for (int kc = 0; kc < 512; kc += 16) {
    if (tid < 128) {
      const int rr = tid >> 2, q = tid & 3;
      const float4 v = *(const float4*)(rin + (r0 + rr) * 512LL + kc + q * 4);
      As[rr][q*4+0] = v.x; As[rr][q*4+1] = v.y; As[rr][q*4+2] = v.z; As[rr][q*4+3] = v.w;
    }
    {
      const int c = tid >> 2, q = tid & 3;
      const float4 v = *(const float4*)(e_w2 + (ll)c * 512 + kc + q * 4);
      Bsh[q*4+0][c] = v.x; Bsh[q*4+1][c] = v.y; Bsh[q*4+2][c] = v.z; Bsh[q*4+3][c] = v.w;
    }
    __syncthreads();
#pragma unroll
    for (int j = 0; j < 16; ++j) {
      const double b0 = (double)Bsh[j][tx*2+0], b1 = (double)Bsh[j][tx*2+1];
      const double a0 = (double)As[ty*4+0][j], a1 = (double)As[ty*4+1][j];
      const double a2 = (double)As[ty*4+2][j], a3 = (double)As[ty*4+3][j];
      acc2[0][0] = fma(a0,b0,acc2[0][0]); acc2[0][1] = fma(a0,b1,acc2[0][1]);
      acc2[1][0] = fma(a1,b0,acc2[1][0]); acc2[1][1] = fma(a1,b1,acc2[1][1]);
      acc2[2][0] = fma(a2,b0,acc2[2][0]); acc2[2][1] = fma(a2,b1,acc2[2][1]);
      acc2[3][0] = fma(a3,b0,acc2[3][0]); acc2[3][1] = fma(a3,b1,acc2[3][1]);
    }
    __syncthreads();
  }
  {
    const float eb0 = e_b2[tx*2+0], eb1 = e_b2[tx*2+1];
#pragma unroll
    for (int i = 0; i < 4; ++i) {
      hbuf[ty*4+i][tx*2+0] = (float)acc2[i][0] + eb0;
      hbuf[ty*4+i][tx*2+1] = (float)acc2[i][1] + eb1;
    }
  }
  __syncthreads();

  if (tid < 32) {
    double s = 0.0;
    for (int l = 0; l < 64; ++l) {
      const float hh = hbuf[tid][l];
      const float q = hh * hh;
      s += (double)q;
    }
    hA[tid] = (float)s;
  }
  __syncthreads();

  float bestv[4]; int besti[4];
#pragma unroll
  for (int i = 0; i < 4; ++i) { bestv[i] = 3.4e38f; besti[i] = 0; }
  for (int c0 = 0; c0 < 2048; c0 += 128) {
#pragma unroll
    for (int m = 0; m < 8; ++m) {
      const int l = m * 256 + tid;
      const int kk = l >> 4, q = l & 15;
      const float4 v = *(const float4*)(cbk + (ll)(c0 + kk) * 64 + q * 4);
      *(float4*)&cbs[kk][q*4] = v;
    }
    if (tid < 128) cns[tid] = cnorm[c0 + tid];
    __syncthreads();
    double dacc[4][4];
#pragma unroll
    for (int i = 0; i < 4; ++i)
#pragma unroll
      for (int j2 = 0; j2 < 4; ++j2) dacc[i][j2] = 0.0;
#pragma unroll
    for (int l = 0; l < 64; l += 4) {
      float4 ha[4], cv[4];
#pragma unroll
      for (int i = 0; i < 4; ++i) ha[i] = *(const float4*)&hbuf[ty*4+i][l];
#pragma unroll
      for (int j2 = 0; j2 < 4; ++j2) cv[j2] = *(const float4*)&cbs[tx + 32*j2][l];
#pragma unroll
      for (int i = 0; i < 4; ++i)
#pragma unroll
        for (int j2 = 0; j2 < 4; ++j2) {
          dacc[i][j2] = fma((double)ha[i].x, (double)cv[j2].x, dacc[i][j2]);
          dacc[i][j2] = fma((double)ha[i].y, (double)cv[j2].y, dacc[i][j2]);
          dacc[i][j2] = fma((double)ha[i].z, (double)cv[j2].z, dacc[i][j2]);
          dacc[i][j2] = fma((double)ha[i].w, (double)cv[j2].w, dacc[i][j2]);
        }
    }
#pragma unroll
    for (int i = 0; i < 4; ++i)
#pragma unroll
      for (int j2 = 0; j2 < 4; ++j2) {
        const float C32 = (float)dacc[i][j2];
        const float D = 2.0f * C32;
        const float E = hA[ty*4+i] + cns[tx + 32*j2];
        const float dist = E - D;
        const int kg = c0 + tx + 32*j2;
        if (dist < bestv[i]) { bestv[i] = dist; besti[i] = kg; }
      }
    __syncthreads();
  }
#pragma unroll
  for (int i = 0; i < 4; ++i) { redv[ty*4+i][tx] = bestv[i]; redi[ty*4+i][tx] = besti[i]; }
  __syncthreads();
  if (tid < 32) {
    float bv = redv[tid][0]; int bi = redi[tid][0];
    for (int x = 1; x < 32; ++x) {
      const float v = redv[tid][x]; const int ii = redi[tid][x];
      if (v < bv || (v == bv && ii < bi)) { bv = v; bi = ii; }
    }
    idxs[tid] = bi;
    dout[IDX_OFF + r0 + tid] = (float)bi;
  }
  __syncthreads();

  {
    const int r = tid >> 3, sl = tid & 7;
    const float* cq = cbk + (ll)idxs[r] * 64 + sl * 8;
    double s = 0.0;
#pragma unroll
    for (int e = 0; e < 8; ++e) {
      const float dx = cq[e] - hbuf[r][sl*8 + e];
      const float sq = dx * dx;
      s += (double)sq;
    }
    lred[tid] = s;
  }
  __syncthreads();
  for (int off = 128; off > 0; off >>= 1) {
    if (tid < off) lred[tid] += lred[tid + off];
    __syncthreads();
  }
  if (tid == 0) lossP[blockIdx.x] = lred[0];

  for (int m = 0; m < 32; ++m) {
    const float4 v = *(const float4*)(rect + (ll)idxs[m] * 1024 + tid * 4);
    *(float4*)(dout + (r0 + m) * 1024 + tid * 4) = v;
  }
}

// =================== k_loss (verbatim round-6 passing version) ===================
__global__ __launch_bounds__(256)
void k_loss(const double* __restrict__ lossP, float* __restrict__ dout)
{
  __shared__ double red[256];
  const int tid = threadIdx.x;
  double s = 0.0;
  for (int i = tid; i < 2048; i += 256) s += lossP[i];
  red[tid] = s;
  __syncthreads();
  for (int off = 128; off > 0; off >>= 1) {
    if (tid < off) red[tid] += red[tid + off];
    __syncthreads();
  }
  if (tid == 0) {
    const float m1 = (float)(red[0] * (1.0 / 4194304.0));
    dout[LOSS_OFF] = m1 + 0.25f * m1;
  }
}

// =================== launch ===================
extern "C" void kernel_launch(void* const* d_in, const int* in_sizes, int n_in,
                              void* d_out, int out_size, void* d_ws, size_t ws_size,
                              hipStream_t stream)
{
  (void)in_sizes; (void)n_in; (void)out_size; (void)ws_size;
  const float* df    = (const float*)d_in[0];
  const float* tf    = (const float*)d_in[1];
  const float* dp_w  = (const float*)d_in[2];
  const float* dp_b  = (const float*)d_in[3];
  const float* tp_w  = (const float*)d_in[4];
  const float* tp_b  = (const float*)d_in[5];
  const float* in_w  = (const float*)d_in[6];
  const float* in_b  = (const float*)d_in[7];
  const float* out_w = (const float*)d_in[8];
  const float* out_b = (const float*)d_in[9];
  const float* n1w   = (const float*)d_in[10];
  const float* n1b   = (const float*)d_in[11];
  const float* n2w   = (const float*)d_in[12];
  const float* n2b   = (const float*)d_in[13];
  const float* e_w1  = (const float*)d_in[14];
  const float* e_b1  = (const float*)d_in[15];
  const float* e_lnw = (const float*)d_in[16];
  const float* e_lnb = (const float*)d_in[17];
  const float* e_w2  = (const float*)d_in[18];
  const float* e_b2  = (const float*)d_in[19];
  const float* cbk   = (const float*)d_in[20];
  const float* d_w1  = (const float*)d_in[21];
  const float* d_b1  = (const float*)d_in[22];
  const float* d_w2  = (const float*)d_in[23];
  const float* d_b2  = (const float*)d_in[24];
  float* out = (float*)d_out;
  float* ws  = (float*)d_ws;

  float* S0 = out;                  // d (raw), later rec overwrites
  float* S1 = out + BN * 512LL;     // lnd2 -> vh_d -> t2
  float* S2 = ws + WF_W1;           // t -> lnt1 -> vh_t -> d2 -> r
  float* RT = ws + WF_RT;
  float* CN = ws + WF_CN;
  double* LP = (double*)(ws + WF_LP);

  const float* wv = in_w + 1024LL * 512LL;
  const float* bv = in_b + 1024LL;

  k_pre<<<129, 256, 0, stream>>>(cbk, d_w1, d_b1, d_w2, d_b2, RT, CN);

  // d -> S0 ; lnd2 = LN(d, n2) -> S1
  k_mmf<1><<<2048, 512, 0, stream>>>(df, nullptr, 48, dp_w, dp_b, nullptr,
                                     n2w, n2b, S0, S1);
  // vh_d -> S1 in-place
  k_mmf<0><<<2048, 512, 0, stream>>>(S1, nullptr, 512, wv, bv, nullptr,
                                     nullptr, nullptr, S1, nullptr);
  // t -> S2
  k_mmf<0><<<2048, 512, 0, stream>>>(tf, nullptr, 768, tp_w, tp_b, nullptr,
                                     nullptr, nullptr, S2, nullptr);
  // t2 = t + vh_d@out_w^T + out_b -> S1 in-place, resid = t(S2)
  k_mmf<0><<<2048, 512, 0, stream>>>(S1, nullptr, 512, out_w, out_b, S2,
                                     nullptr, nullptr, S1, nullptr);
  // lnt1 = LN(t, n1) -> S2 in-place
  k_ln<<<16384, 256, 0, stream>>>(S2, n1w, n1b, S2, 0);
  // vh_t -> S2 in-place
  k_mmf<0><<<2048, 512, 0, stream>>>(S2, nullptr, 512, wv, bv, nullptr,
                                     nullptr, nullptr, S2, nullptr);
  // d2 = d + vh_t@out_w^T + out_b -> S2 in-place, resid = d(S0)
  k_mmf<0><<<2048, 512, 0, stream>>>(S2, nullptr, 512, out_w, out_b, S0,
                                     nullptr, nullptr, S2, nullptr);
  // u = [d2|t2]@e_w1^T + e_b1; r = relu(LN(u)) -> S2 in-place
  k_mmf<2><<<2048, 512, 0, stream>>>(S2, S1, 1024, e_w1, e_b1, nullptr,
                                     e_lnw, e_lnb, S2, nullptr);
  // head + loss
  k_head<<<2048, 256, 0, stream>>>(S2, e_w2, e_b2, cbk, CN, RT, out, LP);
  k_loss<<<1, 256, 0, stream>>>(LP, out);
}

// Round 9
// 5033.705 us; speedup vs baseline: 2.3548x; 1.0333x over previous
//
#include <hip/hip_runtime.h>
#include <math.h>

typedef long long ll;
typedef double f64x4 __attribute__((ext_vector_type(4)));

#define BN 65536LL
#define LOSS_OFF (BN * 1024LL)
#define IDX_OFF  (LOSS_OFF + 1LL)

// ---- workspace layout (float offsets) ----
#define WF_W1 0LL                          // B x 512 scratch (ws slot S2)
#define WF_RT (WF_W1 + BN * 512LL)         // rec_table 2048 x 1024
#define WF_CN (WF_RT + 2048LL * 1024LL)    // cnorm 2048 (fp32)
#define WF_LP (WF_CN + 2048LL)             // loss partials 2048 doubles

#define BSTR 522   // B LDS row stride (f32)

// =================== k_mmf: fp64-MFMA GEMM, double-buffered LDS ===================
// 512 threads = 8 waves. Block tile: 32 rows x 512 cols. Wave: 32 rows x 64 cols
// (2 m-tiles x 4 n-tiles of mfma_f64_16x16x4) — B LDS reads are block-optimal.
// Per-output-element MFMA chain is bit-identical to the round-8 passing kernel.
// MODE 0: raw -> Y.  MODE 1: raw -> Y, LN(raw) -> Y2.  MODE 2: relu(LN(raw)) -> Y.
template<int MODE>
__global__ __launch_bounds__(512, 4)
void k_mmf(const float* __restrict__ A0, const float* __restrict__ A1, int K,
           const float* __restrict__ W, const float* __restrict__ bias,
           const float* __restrict__ resid,
           const float* __restrict__ lnw, const float* __restrict__ lnb,
           float* __restrict__ Y, float* __restrict__ Y2)
{
  __shared__ double As64[2][16][33];       // [buf][k][row] f64
  __shared__ double poolB[2][4176];        // [buf] 16 x 522 f32
  __shared__ float msh[32], rsh[32];
  double (*red)[128] = (double(*)[128])poolB[0];  // aliased post-loop (after final barrier)

  const int tid = threadIdx.x;
  const int w = tid >> 6, l = tid & 63;
  const int q16 = l >> 4, l15 = l & 15;
  const int cbase = w * 64;                // wave col slice (8 x 64 = 512)
  const ll r0 = (ll)blockIdx.x * 32;
  const int strideA0 = A1 ? 512 : K;
  const int arow = tid >> 4, ak = tid & 15;

  f64x4 acc[8];                            // acc[mt*4+nt]
#pragma unroll
  for (int f = 0; f < 8; ++f) acc[f] = (f64x4){0.0, 0.0, 0.0, 0.0};

  // ---- prologue: stage kc=0 into buf 0 ----
  {
    float av = A0[(r0 + arow) * (ll)strideA0 + ak];   // ak < 16 < 512: always A0
    float4 bv4[4];
#pragma unroll
    for (int m = 0; m < 4; ++m) {
      const int s = m * 512 + tid;
      const int col = s >> 2, kq = s & 3;
      bv4[m] = *(const float4*)(W + (ll)col * K + kq * 4);
    }
    As64[0][ak][arow] = (double)av;
    float* B0 = (float*)poolB[0];
#pragma unroll
    for (int m = 0; m < 4; ++m) {
      const int s = m * 512 + tid;
      const int col = s >> 2, kq = s & 3;
      B0[(kq*4+0)*BSTR + col] = bv4[m].x;
      B0[(kq*4+1)*BSTR + col] = bv4[m].y;
      B0[(kq*4+2)*BSTR + col] = bv4[m].z;
      B0[(kq*4+3)*BSTR + col] = bv4[m].w;
    }
  }
  __syncthreads();

  int cur = 0;
  for (int kc = 0; kc < K; kc += 16) {
    const bool more = (kc + 16) < K;
    float av; float4 bv4[4];
    if (more) {                            // issue next-step loads EARLY
      const int cidx = kc + 16 + ak;
      if (A1 && cidx >= 512) av = A1[(r0 + arow) * 512LL + (cidx - 512)];
      else                   av = A0[(r0 + arow) * (ll)strideA0 + cidx];
#pragma unroll
      for (int m = 0; m < 4; ++m) {
        const int s = m * 512 + tid;
        const int col = s >> 2, kq = s & 3;
        bv4[m] = *(const float4*)(W + (ll)col * K + kc + 16 + kq * 4);
      }
    }
    // MFMA on current buffer: per kq, 2 A reads + 4 B reads feed 8 MFMAs
    {
      const double (*A_)[33] = As64[cur];
      const float* B_ = (const float*)poolB[cur];
#pragma unroll
      for (int kq = 0; kq < 4; ++kq) {
        const int kk = kq * 4 + q16;
        const double a0 = A_[kk][l15];          // rows 0-15
        const double a1 = A_[kk][16 + l15];     // rows 16-31
#pragma unroll
        for (int nt = 0; nt < 4; ++nt) {
          const double b = (double)B_[kk * BSTR + cbase + nt*16 + l15];
          acc[nt]     = __builtin_amdgcn_mfma_f64_16x16x4f64(a0, b, acc[nt],     0, 0, 0);
          acc[4 + nt] = __builtin_amdgcn_mfma_f64_16x16x4f64(a1, b, acc[4 + nt], 0, 0, 0);
        }
      }
    }
    if (more) {                            // write-late into next buffer
      As64[cur ^ 1][ak][arow] = (double)av;
      float* Bn = (float*)poolB[cur ^ 1];
#pragma unroll
      for (int m = 0; m < 4; ++m) {
        const int s = m * 512 + tid;
        const int col = s >> 2, kq = s & 3;
        Bn[(kq*4+0)*BSTR + col] = bv4[m].x;
        Bn[(kq*4+1)*BSTR + col] = bv4[m].y;
        Bn[(kq*4+2)*BSTR + col] = bv4[m].z;
        Bn[(kq*4+3)*BSTR + col] = bv4[m].w;
      }
    }
    __syncthreads();
    cur ^= 1;
  }

  // epilogue: acc[mt*4+nt][bb] -> row = mt*16 + q16*4 + bb, col = cbase + nt*16 + l15
  float o[8][4];
#pragma unroll
  for (int mt = 0; mt < 2; ++mt)
#pragma unroll
    for (int nt = 0; nt < 4; ++nt)
#pragma unroll
      for (int bb = 0; bb < 4; ++bb) {
        const int row = mt*16 + q16*4 + bb;
        const int col = cbase + nt*16 + l15;
        const float mm = (float)acc[mt*4+nt][bb];   // fl(matmul)
        const float y1 = mm + bias[col];            // fl(+bias)
        o[mt*4+nt][bb] = resid ? (resid[(r0 + row) * 512LL + col] + y1) : y1; // fl(resid+.)
      }

  if (MODE != 2) {
#pragma unroll
    for (int mt = 0; mt < 2; ++mt)
#pragma unroll
      for (int nt = 0; nt < 4; ++nt)
#pragma unroll
        for (int bb = 0; bb < 4; ++bb) {
          const int row = mt*16 + q16*4 + bb;
          const int col = cbase + nt*16 + l15;
          Y[(r0 + row) * 512LL + col] = o[mt*4+nt][bb];
        }
  }
  if (MODE == 0) return;

  // fused LN (np-fp32 boundary chain, fp64 sums — reassociation-harmless class)
#pragma unroll
  for (int mt = 0; mt < 2; ++mt)
#pragma unroll
    for (int bb = 0; bb < 4; ++bb) {
      const int row = mt*16 + q16*4 + bb;
      double s = 0.0;
#pragma unroll
      for (int nt = 0; nt < 4; ++nt) s += (double)o[mt*4+nt][bb];
      red[row][w*16 + l15] = s;
    }
  __syncthreads();
  if (tid < 32) {
    double s = 0.0;
    for (int x = 0; x < 128; ++x) s += red[tid][x];
    msh[tid] = (float)(s * (1.0 / 512.0));
  }
  __syncthreads();
#pragma unroll
  for (int mt = 0; mt < 2; ++mt)
#pragma unroll
    for (int bb = 0; bb < 4; ++bb) {
      const int row = mt*16 + q16*4 + bb;
      const float m32 = msh[row];
      double s2 = 0.0;
#pragma unroll
      for (int nt = 0; nt < 4; ++nt) {
        o[mt*4+nt][bb] = o[mt*4+nt][bb] - m32;           // fp32 op
        const float sq = o[mt*4+nt][bb] * o[mt*4+nt][bb]; // fp32 op
        s2 += (double)sq;
      }
      red[row][w*16 + l15] = s2;
    }
  __syncthreads();
  if (tid < 32) {
    double s = 0.0;
    for (int x = 0; x < 128; ++x) s += red[tid][x];
    const float v32 = (float)(s * (1.0 / 512.0));
    const float a32 = v32 + 1e-5f;
    const float sq32 = (float)sqrt((double)a32);   // CR fp32 sqrt
    rsh[tid] = (float)(1.0 / (double)sq32);        // CR fp32 div
  }
  __syncthreads();
  {
    float* dst = (MODE == 1) ? Y2 : Y;
#pragma unroll
    for (int mt = 0; mt < 2; ++mt)
#pragma unroll
      for (int bb = 0; bb < 4; ++bb) {
        const int row = mt*16 + q16*4 + bb;
        const float rs = rsh[row];
#pragma unroll
        for (int nt = 0; nt < 4; ++nt) {
          const int col = cbase + nt*16 + l15;
          float v = ((o[mt*4+nt][bb] * rs) * lnw[col]) + lnb[col]; // fp32 chain
          if (MODE == 2) v = fmaxf(v, 0.f);
          dst[(r0 + row) * 512LL + col] = v;
        }
      }
  }
}

// =================== k_ln (verbatim passing version; used for lnt1) ===================
__global__ __launch_bounds__(256)
void k_ln(const float* __restrict__ X, const float* __restrict__ w,
          const float* __restrict__ b, float* __restrict__ Y, int relu)
{
  const int tid = threadIdx.x;
  const int lane = tid & 63, wid = tid >> 6;
  const ll row = (ll)blockIdx.x * 4 + wid;
  const ll base = row * 512;

  float xv[8];
#pragma unroll
  for (int j = 0; j < 8; ++j) xv[j] = X[base + j*64 + lane];

  double s = 0.0;
#pragma unroll
  for (int j = 0; j < 8; ++j) s += (double)xv[j];
#pragma unroll
  for (int off = 32; off > 0; off >>= 1) s += __shfl_down(s, off, 64);
  s = __shfl(s, 0, 64);
  const float m32 = (float)(s * (1.0 / 512.0));

  float xm[8];
  double s2 = 0.0;
#pragma unroll
  for (int j = 0; j < 8; ++j) {
    xm[j] = xv[j] - m32;
    const float sq = xm[j] * xm[j];
    s2 += (double)sq;
  }
#pragma unroll
  for (int off = 32; off > 0; off >>= 1) s2 += __shfl_down(s2, off, 64);
  s2 = __shfl(s2, 0, 64);
  const float v32 = (float)(s2 * (1.0 / 512.0));
  const float a32 = v32 + 1e-5f;
  const float sq32 = (float)sqrt((double)a32);
  const float rs32 = (float)(1.0 / (double)sq32);

#pragma unroll
  for (int j = 0; j < 8; ++j) {
    float o = ((xm[j] * rs32) * w[j*64 + lane]) + b[j*64 + lane];
    if (relu) o = fmaxf(o, 0.f);
    Y[base + j*64 + lane] = o;
  }
}

// =================== k_pre (verbatim passing version) ===================
__global__ __launch_bounds__(256)
void k_pre(const float* __restrict__ cbk, const float* __restrict__ d_w1,
           const float* __restrict__ d_b1, const float* __restrict__ d_w2,
           const float* __restrict__ d_b2,
           float* __restrict__ rect, float* __restrict__ cnorm)
{
  __shared__ float cbs16[16][68];
  __shared__ float pbuf[16][516];
  const int tid = threadIdx.x;
  const int bb = blockIdx.x;

  if (bb < 128) {
    const int e0 = bb * 16;
    {
      const int e = tid >> 4, q = tid & 15;
      const float4 v = *(const float4*)(cbk + (ll)(e0 + e) * 64 + q * 4);
      *(float4*)&cbs16[e][q*4] = v;
    }
    __syncthreads();
    {
      double pa0[16], pa1[16];
#pragma unroll
      for (int e = 0; e < 16; ++e) { pa0[e] = 0.0; pa1[e] = 0.0; }
      const int i0 = tid * 2;
      for (int l = 0; l < 64; l += 4) {
        const float4 w0 = *(const float4*)(d_w1 + (ll)i0 * 64 + l);
        const float4 w1 = *(const float4*)(d_w1 + (ll)(i0 + 1) * 64 + l);
#pragma unroll
        for (int e = 0; e < 16; ++e) {
          const float4 c4 = *(const float4*)&cbs16[e][l];
          pa0[e] = fma((double)w0.x,(double)c4.x, fma((double)w0.y,(double)c4.y,
                   fma((double)w0.z,(double)c4.z, fma((double)w0.w,(double)c4.w, pa0[e]))));
          pa1[e] = fma((double)w1.x,(double)c4.x, fma((double)w1.y,(double)c4.y,
                   fma((double)w1.z,(double)c4.z, fma((double)w1.w,(double)c4.w, pa1[e]))));
        }
      }
      const double db0 = (double)d_b1[i0], db1 = (double)d_b1[i0 + 1];
#pragma unroll
      for (int e = 0; e < 16; ++e) {
        pbuf[e][i0]     = (float)fmax(pa0[e] + db0, 0.0);
        pbuf[e][i0 + 1] = (float)fmax(pa1[e] + db1, 0.0);
      }
    }
    __syncthreads();
    {
      double ra[16][4];
#pragma unroll
      for (int e = 0; e < 16; ++e)
#pragma unroll
        for (int k = 0; k < 4; ++k) ra[e][k] = 0.0;
      const int o4 = tid * 4;
      for (int i4 = 0; i4 < 512; i4 += 4) {
        const float4 w0 = *(const float4*)(d_w2 + (ll)(o4+0) * 512 + i4);
        const float4 w1 = *(const float4*)(d_w2 + (ll)(o4+1) * 512 + i4);
        const float4 w2 = *(const float4*)(d_w2 + (ll)(o4+2) * 512 + i4);
        const float4 w3 = *(const float4*)(d_w2 + (ll)(o4+3) * 512 + i4);
#pragma unroll
        for (int e = 0; e < 16; ++e) {
          const float4 p4 = *(const float4*)&pbuf[e][i4];
          ra[e][0] = fma((double)w0.x,(double)p4.x, fma((double)w0.y,(double)p4.y,
                     fma((double)w0.z,(double)p4.z, fma((double)w0.w,(double)p4.w, ra[e][0]))));
          ra[e][1] = fma((double)w1.x,(double)p4.x, fma((double)w1.y,(double)p4.y,
                     fma((double)w1.z,(double)p4.z, fma((double)w1.w,(double)p4.w, ra[e][1]))));
          ra[e][2] = fma((double)w2.x,(double)p4.x, fma((double)w2.y,(double)p4.y,
                     fma((double)w2.z,(double)p4.z, fma((double)w2.w,(double)p4.w, ra[e][2]))));
          ra[e][3] = fma((double)w3.x,(double)p4.x, fma((double)w3.y,(double)p4.y,
                     fma((double)w3.z,(double)p4.z, fma((double)w3.w,(double)p4.w, ra[e][3]))));
        }
      }
      const float4 db = *(const float4*)(d_b2 + o4);
#pragma unroll
      for (int e = 0; e < 16; ++e) {
        *(float4*)(rect + (ll)(e0 + e) * 1024 + o4) =
          make_float4((float)(ra[e][0]+(double)db.x), (float)(ra[e][1]+(double)db.y),
                      (float)(ra[e][2]+(double)db.z), (float)(ra[e][3]+(double)db.w));
      }
    }
  } else {
    for (int k = tid; k < 2048; k += 256) {
      double s = 0.0;
      for (int l = 0; l < 64; ++l) {
        const float c = cbk[(ll)k * 64 + l];
        const float q = c * c;
        s += (double)q;
      }
      cnorm[k] = (float)s;
    }
  }
}

// =================== k_head (verbatim passing version: vector dist) ===================
__global__ __launch_bounds__(256)
void k_head(const float* __restrict__ rin, const float* __restrict__ e_w2,
            const float* __restrict__ e_b2, const float* __restrict__ cbk,
            const float* __restrict__ cnorm, const float* __restrict__ rect,
            float* __restrict__ dout, double* __restrict__ lossP)
{
  __shared__ float As[32][17];
  __shared__ float Bsh[16][68];
  __shared__ float hbuf[32][68];
  __shared__ float hA[32];
  __shared__ float cbs[128][68];
  __shared__ float cns[128];
  __shared__ float redv[32][33];
  __shared__ int   redi[32][33];
  __shared__ int   idxs[32];
  __shared__ double lred[256];
  const int tid = threadIdx.x;
  const int tx = tid & 31, ty = tid >> 5;
  const ll r0 = (ll)blockIdx.x * 32;

  double acc2[4][2];
#pragma unroll
  for (int i = 0; i < 4; ++i) { acc2[i][0] = 0.0; acc2[i][1] = 0.0; }
  for (int kc = 0; kc < 512; kc += 16) {
    if (tid < 128) {
      const int rr = tid >> 2, q = tid & 3;
      const float4 v = *(const float4*)(rin + (r0 + rr) * 512LL + kc + q * 4);
      As[rr][q*4+0] = v.x; As[rr][q*4+1] = v.y; As[rr][q*4+2] = v.z; As[rr][q*4+3] = v.w;
    }
    {
      const int c = tid >> 2, q = tid & 3;
      const float4 v = *(const float4*)(e_w2 + (ll)c * 512 + kc + q * 4);
      Bsh[q*4+0][c] = v.x; Bsh[q*4+1][c] = v.y; Bsh[q*4+2][c] = v.z; Bsh[q*4+3][c] = v.w;
    }
    __syncthreads();
#pragma unroll
    for (int j = 0; j < 16; ++j) {
      const double b0 = (double)Bsh[j][tx*2+0], b1 = (double)Bsh[j][tx*2+1];
      const double a0 = (double)As[ty*4+0][j], a1 = (double)As[ty*4+1][j];
      const double a2 = (double)As[ty*4+2][j], a3 = (double)As[ty*4+3][j];
      acc2[0][0] = fma(a0,b0,acc2[0][0]); acc2[0][1] = fma(a0,b1,acc2[0][1]);
      acc2[1][0] = fma(a1,b0,acc2[1][0]); acc2[1][1] = fma(a1,b1,acc2[1][1]);
      acc2[2][0] = fma(a2,b0,acc2[2][0]); acc2[2][1] = fma(a2,b1,acc2[2][1]);
      acc2[3][0] = fma(a3,b0,acc2[3][0]); acc2[3][1] = fma(a3,b1,acc2[3][1]);
    }
    __syncthreads();
  }
  {
    const float eb0 = e_b2[tx*2+0], eb1 = e_b2[tx*2+1];
#pragma unroll
    for (int i = 0; i < 4; ++i) {
      hbuf[ty*4+i][tx*2+0] = (float)acc2[i][0] + eb0;
      hbuf[ty*4+i][tx*2+1] = (float)acc2[i][1] + eb1;
    }
  }
  __syncthreads();

  if (tid < 32) {
    double s = 0.0;
    for (int l = 0; l < 64; ++l) {
      const float hh = hbuf[tid][l];
      const float q = hh * hh;
      s += (double)q;
    }
    hA[tid] = (float)s;
  }
  __syncthreads();

  float bestv[4]; int besti[4];
#pragma unroll
  for (int i = 0; i < 4; ++i) { bestv[i] = 3.4e38f; besti[i] = 0; }
  for (int c0 = 0; c0 < 2048; c0 += 128) {
#pragma unroll
    for (int m = 0; m < 8; ++m) {
      const int l = m * 256 + tid;
      const int kk = l >> 4, q = l & 15;
      const float4 v = *(const float4*)(cbk + (ll)(c0 + kk) * 64 + q * 4);
      *(float4*)&cbs[kk][q*4] = v;
    }
    if (tid < 128) cns[tid] = cnorm[c0 + tid];
    __syncthreads();
    double dacc[4][4];
#pragma unroll
    for (int i = 0; i < 4; ++i)
#pragma unroll
      for (int j2 = 0; j2 < 4; ++j2) dacc[i][j2] = 0.0;
#pragma unroll
    for (int l = 0; l < 64; l += 4) {
      float4 ha[4], cv[4];
#pragma unroll
      for (int i = 0; i < 4; ++i) ha[i] = *(const float4*)&hbuf[ty*4+i][l];
#pragma unroll
      for (int j2 = 0; j2 < 4; ++j2) cv[j2] = *(const float4*)&cbs[tx + 32*j2][l];
#pragma unroll
      for (int i = 0; i < 4; ++i)
#pragma unroll
        for (int j2 = 0; j2 < 4; ++j2) {
          dacc[i][j2] = fma((double)ha[i].x, (double)cv[j2].x, dacc[i][j2]);
          dacc[i][j2] = fma((double)ha[i].y, (double)cv[j2].y, dacc[i][j2]);
          dacc[i][j2] = fma((double)ha[i].z, (double)cv[j2].z, dacc[i][j2]);
          dacc[i][j2] = fma((double)ha[i].w, (double)cv[j2].w, dacc[i][j2]);
        }
    }
#pragma unroll
    for (int i = 0; i < 4; ++i)
#pragma unroll
      for (int j2 = 0; j2 < 4; ++j2) {
        const float C32 = (float)dacc[i][j2];
        const float D = 2.0f * C32;
        const float E = hA[ty*4+i] + cns[tx + 32*j2];
        const float dist = E - D;
        const int kg = c0 + tx + 32*j2;
        if (dist < bestv[i]) { bestv[i] = dist; besti[i] = kg; }
      }
    __syncthreads();
  }
#pragma unroll
  for (int i = 0; i < 4; ++i) { redv[ty*4+i][tx] = bestv[i]; redi[ty*4+i][tx] = besti[i]; }
  __syncthreads();
  if (tid < 32) {
    float bv = redv[tid][0]; int bi = redi[tid][0];
    for (int x = 1; x < 32; ++x) {
      const float v = redv[tid][x]; const int ii = redi[tid][x];
      if (v < bv || (v == bv && ii < bi)) { bv = v; bi = ii; }
    }
    idxs[tid] = bi;
    dout[IDX_OFF + r0 + tid] = (float)bi;
  }
  __syncthreads();

  {
    const int r = tid >> 3, sl = tid & 7;
    const float* cq = cbk + (ll)idxs[r] * 64 + sl * 8;
    double s = 0.0;
#pragma unroll
    for (int e = 0; e < 8; ++e) {
      const float dx = cq[e] - hbuf[r][sl*8 + e];
      const float sq = dx * dx;
      s += (double)sq;
    }
    lred[tid] = s;
  }
  __syncthreads();
  for (int off = 128; off > 0; off >>= 1) {
    if (tid < off) lred[tid] += lred[tid + off];
    __syncthreads();
  }
  if (tid == 0) lossP[blockIdx.x] = lred[0];

  for (int m = 0; m < 32; ++m) {
    const float4 v = *(const float4*)(rect + (ll)idxs[m] * 1024 + tid * 4);
    *(float4*)(dout + (r0 + m) * 1024 + tid * 4) = v;
  }
}

// =================== k_loss (verbatim passing version) ===================
__global__ __launch_bounds__(256)
void k_loss(const double* __restrict__ lossP, float* __restrict__ dout)
{
  __shared__ double red[256];
  const int tid = threadIdx.x;
  double s = 0.0;
  for (int i = tid; i < 2048; i += 256) s += lossP[i];
  red[tid] = s;
  __syncthreads();
  for (int off = 128; off > 0; off >>= 1) {
    if (tid < off) red[tid] += red[tid + off];
    __syncthreads();
  }
  if (tid == 0) {
    const float m1 = (float)(red[0] * (1.0 / 4194304.0));
    dout[LOSS_OFF] = m1 + 0.25f * m1;
  }
}

// =================== launch ===================
extern "C" void kernel_launch(void* const* d_in, const int* in_sizes, int n_in,
                              void* d_out, int out_size, void* d_ws, size_t ws_size,
                              hipStream_t stream)
{
  (void)in_sizes; (void)n_in; (void)out_size; (void)ws_size;
  const float* df    = (const float*)d_in[0];
  const float* tf    = (const float*)d_in[1];
  const float* dp_w  = (const float*)d_in[2];
  const float* dp_b  = (const float*)d_in[3];
  const float* tp_w  = (const float*)d_in[4];
  const float* tp_b  = (const float*)d_in[5];
  const float* in_w  = (const float*)d_in[6];
  const float* in_b  = (const float*)d_in[7];
  const float* out_w = (const float*)d_in[8];
  const float* out_b = (const float*)d_in[9];
  const float* n1w   = (const float*)d_in[10];
  const float* n1b   = (const float*)d_in[11];
  const float* n2w   = (const float*)d_in[12];
  const float* n2b   = (const float*)d_in[13];
  const float* e_w1  = (const float*)d_in[14];
  const float* e_b1  = (const float*)d_in[15];
  const float* e_lnw = (const float*)d_in[16];
  const float* e_lnb = (const float*)d_in[17];
  const float* e_w2  = (const float*)d_in[18];
  const float* e_b2  = (const float*)d_in[19];
  const float* cbk   = (const float*)d_in[20];
  const float* d_w1  = (const float*)d_in[21];
  const float* d_b1  = (const float*)d_in[22];
  const float* d_w2  = (const float*)d_in[23];
  const float* d_b2  = (const float*)d_in[24];
  float* out = (float*)d_out;
  float* ws  = (float*)d_ws;

  float* S0 = out;                  // d (raw), later rec overwrites
  float* S1 = out + BN * 512LL;     // lnd2 -> vh_d -> t2
  float* S2 = ws + WF_W1;           // t -> lnt1 -> vh_t -> d2 -> r
  float* RT = ws + WF_RT;
  float* CN = ws + WF_CN;
  double* LP = (double*)(ws + WF_LP);

  const float* wv = in_w + 1024LL * 512LL;
  const float* bv = in_b + 1024LL;

  k_pre<<<129, 256, 0, stream>>>(cbk, d_w1, d_b1, d_w2, d_b2, RT, CN);

  // d -> S0 ; lnd2 = LN(d, n2) -> S1
  k_mmf<1><<<2048, 512, 0, stream>>>(df, nullptr, 48, dp_w, dp_b, nullptr,
                                     n2w, n2b, S0, S1);
  // vh_d -> S1 in-place
  k_mmf<0><<<2048, 512, 0, stream>>>(S1, nullptr, 512, wv, bv, nullptr,
                                     nullptr, nullptr, S1, nullptr);
  // t -> S2
  k_mmf<0><<<2048, 512, 0, stream>>>(tf, nullptr, 768, tp_w, tp_b, nullptr,
                                     nullptr, nullptr, S2, nullptr);
  // t2 = t + vh_d@out_w^T + out_b -> S1 in-place, resid = t(S2)
  k_mmf<0><<<2048, 512, 0, stream>>>(S1, nullptr, 512, out_w, out_b, S2,
                                     nullptr, nullptr, S1, nullptr);
  // lnt1 = LN(t, n1) -> S2 in-place
  k_ln<<<16384, 256, 0, stream>>>(S2, n1w, n1b, S2, 0);
  // vh_t -> S2 in-place
  k_mmf<0><<<2048, 512, 0, stream>>>(S2, nullptr, 512, wv, bv, nullptr,
                                     nullptr, nullptr, S2, nullptr);
  // d2 = d + vh_t@out_w^T + out_b -> S2 in-place, resid = d(S0)
  k_mmf<0><<<2048, 512, 0, stream>>>(S2, nullptr, 512, out_w, out_b, S0,
                                     nullptr, nullptr, S2, nullptr);
  // u = [d2|t2]@e_w1^T + e_b1; r = relu(LN(u)) -> S2 in-place
  k_mmf<2><<<2048, 512, 0, stream>>>(S2, S1, 1024, e_w1, e_b1, nullptr,
                                     e_lnw, e_lnb, S2, nullptr);
  // head + loss
  k_head<<<2048, 256, 0, stream>>>(S2, e_w2, e_b2, cbk, CN, RT, out, LP);
  k_loss<<<1, 256, 0, stream>>>(LP, out);
}